// Round 3
// baseline (1953.264 us; speedup 1.0000x reference)
//
#include <hip/hip_runtime.h>
#include <hip/hip_bf16.h>
#include <math.h>

#define NN 50000
#define NE 800000
#define D 128
#define NBATCH 32
#define NLAYERS 3
#define SCANB ((NN + 1023) / 1024)   // 49

typedef __attribute__((ext_vector_type(8))) short bf16x8;
typedef __attribute__((ext_vector_type(4))) float f32x4;

__device__ __forceinline__ float silu_f(float x) {
    return x / (1.0f + __expf(-x));
}
__device__ __forceinline__ ushort f2b(float v) {
    __hip_bfloat16 b = __float2bfloat16(v);
    return *(ushort*)&b;
}

// ---------------- time MLP ----------------
__global__ void k_time_mlp(const float* __restrict__ te,
                           const float* __restrict__ w1, const float* __restrict__ b1,
                           const float* __restrict__ w2, const float* __restrict__ b2,
                           float* __restrict__ tp) {
    __shared__ float s_in[D];
    __shared__ float s_hid[D];
    const int b = blockIdx.x;
    const int j = threadIdx.x;
    s_in[j] = te[b * D + j];
    __syncthreads();
    float acc = b1[j];
    for (int k = 0; k < D; ++k) acc = fmaf(s_in[k], w1[k * D + j], acc);
    s_hid[j] = silu_f(acc);
    __syncthreads();
    float acc2 = b2[j];
    for (int k = 0; k < D; ++k) acc2 = fmaf(s_hid[k], w2[k * D + j], acc2);
    tp[b * D + j] = acc2;
}

// ---------------- h = x + tp[batch]; also h_bf16 ----------------
__global__ void k_init_h(const float* __restrict__ x, const float* __restrict__ tp,
                         const int* __restrict__ batch, float* __restrict__ h,
                         ushort* __restrict__ hb) {
    int idx = blockIdx.x * 256 + threadIdx.x;
    int n = idx >> 7, c = idx & 127;
    float v = x[idx] + tp[batch[n] * D + c];
    h[idx] = v;
    hb[idx] = f2b(v);
}

// ---------------- integer degree ----------------
__global__ void k_deg(const int* __restrict__ col, unsigned int* __restrict__ deg) {
    int e = blockIdx.x * 256 + threadIdx.x;
    atomicAdd(&deg[col[e]], 1u);
}

// ---------------- exclusive scan over deg (3 kernels) ----------------
__global__ void k_scan_a(const unsigned int* __restrict__ deg, unsigned int* __restrict__ part) {
    __shared__ unsigned int sl[256];
    int b = blockIdx.x, t = threadIdx.x;
    unsigned int s = 0;
    #pragma unroll
    for (int i = 0; i < 4; ++i) {
        int idx = b * 1024 + t * 4 + i;
        if (idx < NN) s += deg[idx];
    }
    sl[t] = s; __syncthreads();
    for (int off = 128; off; off >>= 1) {
        if (t < off) sl[t] += sl[t + off];
        __syncthreads();
    }
    if (t == 0) part[b] = sl[0];
}
__global__ void k_scan_b(unsigned int* __restrict__ part) {
    __shared__ unsigned int sp[64];
    int t = threadIdx.x;
    sp[t] = (t < SCANB) ? part[t] : 0u;
    __syncthreads();
    if (t == 0) {
        unsigned int run = 0;
        for (int i = 0; i < SCANB; ++i) { unsigned int v = sp[i]; sp[i] = run; run += v; }
    }
    __syncthreads();
    if (t < SCANB) part[t] = sp[t];
}
__global__ void k_scan_c(const unsigned int* __restrict__ deg, const unsigned int* __restrict__ part,
                         unsigned int* __restrict__ starts) {
    __shared__ unsigned int sl[256];
    int b = blockIdx.x, t = threadIdx.x;
    unsigned int v4[4]; unsigned int s = 0;
    #pragma unroll
    for (int i = 0; i < 4; ++i) {
        int idx = b * 1024 + t * 4 + i;
        v4[i] = (idx < NN) ? deg[idx] : 0u;
        s += v4[i];
    }
    sl[t] = s; __syncthreads();
    if (t == 0) {
        unsigned int run = 0;
        for (int i = 0; i < 256; ++i) { unsigned int x = sl[i]; sl[i] = run; run += x; }
    }
    __syncthreads();
    unsigned int off = part[b] + sl[t];
    #pragma unroll
    for (int i = 0; i < 4; ++i) {
        int idx = b * 1024 + t * 4 + i;
        if (idx < NN) { starts[idx] = off; off += v4[i]; }
    }
}

// ---------------- counting-sort placement (cursor == starts, destructive) ----------------
__global__ void k_sort(const int* __restrict__ ei, unsigned int* __restrict__ cursor,
                       int* __restrict__ srow, int* __restrict__ scol) {
    int e = blockIdx.x * 256 + threadIdx.x;
    int r = ei[e], c = ei[NE + e];
    unsigned int p = atomicAdd(&cursor[c], 1u);
    srow[p] = r; scol[p] = c;
}

// ---------------- per-edge distance (sorted order) ----------------
__global__ void k_dist(const int* __restrict__ srow, const int* __restrict__ scol,
                       const float* __restrict__ pos, float* __restrict__ sdist) {
    int e = blockIdx.x * 256 + threadIdx.x;
    int r = srow[e], c = scol[e];
    float dx = pos[r * 3 + 0] - pos[c * 3 + 0];
    float dy = pos[r * 3 + 1] - pos[c * 3 + 1];
    float dz = pos[r * 3 + 2] - pos[c * 3 + 2];
    sdist[e] = sqrtf(dx * dx + dy * dy + dz * dz);
}

// ---------------- weight pre-pack (fragment-major bf16) ----------------
__global__ void k_pack(const float* __restrict__ W, ushort* __restrict__ out,
                       int KSlog2, int layerStrideW, int totalPerLayer) {
    int t = blockIdx.x * 256 + threadIdx.x;
    int l = t / totalPerLayer;
    int r = t - l * totalPerLayer;
    int j = r & 7;
    int lane = (r >> 3) & 63;
    int ks = (r >> 9) & ((1 << KSlog2) - 1);
    int ct = r >> (9 + KSlog2);
    int k = ks * 32 + ((lane >> 4) << 3) + j;
    int n = ct * 16 + (lane & 15);
    out[t] = f2b(W[(size_t)l * layerStrideW + k * 128 + n]);
}

// ---------------- fused edge MLP (MFMA) + in-LDS pre-agg + sparse scatter ----------------
// 256 threads = 4 waves; 64 sorted edges per block; wave w owns edge rows [w*16, w*16+16).
__global__ __launch_bounds__(256, 4)
void k_edge(const ushort* __restrict__ hb,
            const int* __restrict__ srow, const int* __restrict__ scol,
            const float* __restrict__ sdist,
            const ushort* __restrict__ pw1, const ushort* __restrict__ pw2,
            const float* __restrict__ w1f, const float* __restrict__ b1,
            const float* __restrict__ b2,
            float* __restrict__ agg) {
    __shared__ float sAgg[64][128];                 // 32 KB; first 16 KB aliased as sHid
    ushort (*sHid)[128] = (ushort(*)[128])sAgg;     // [64][128] bf16, swizzled
    __shared__ int sCol[64];
    __shared__ int sSlot[64];
    __shared__ unsigned long long sMask;

    const int t = threadIdx.x;
    const int ebase = blockIdx.x * 64;

    if (t < 64) {   // exactly wave 0
        int c = scol[ebase + t];
        sCol[t] = c;
        bool flag = (t == 0) || (scol[ebase + t - 1] != c);
        unsigned long long m = __ballot(flag);
        sSlot[t] = t - __builtin_clzll(m << (63 - t));   // first-occurrence index of my run
        if (t == 0) sMask = m;
    }
    __syncthreads();

    const int lane = t & 63;
    const int wv = t >> 6;
    const int we0 = wv * 16;
    const int lane16 = lane & 15;
    const int lg = lane >> 4;
    const int ar = we0 + lane16;          // A row this lane serves
    const int eg = ebase + ar;

    // ---- direct global->register A gather (zero reuse; no LDS) ----
    const int nc = sCol[ar];
    const int nr = srow[eg];
    const ushort* pc = hb + (size_t)nc * D;
    const ushort* pr = hb + (size_t)nr * D;
    bf16x8 a[8];
    #pragma unroll
    for (int ks = 0; ks < 4; ++ks) a[ks]     = *(const bf16x8*)(pc + (ks * 4 + lg) * 8);
    #pragma unroll
    for (int ks = 0; ks < 4; ++ks) a[4 + ks] = *(const bf16x8*)(pr + (ks * 4 + lg) * 8);

    // ---- GEMM1: [64 x 256] @ W1 ----
    f32x4 acc[8];
    #pragma unroll
    for (int ct = 0; ct < 8; ++ct) acc[ct] = (f32x4){0.f, 0.f, 0.f, 0.f};
    #pragma unroll
    for (int ks = 0; ks < 8; ++ks) {
        #pragma unroll
        for (int ct = 0; ct < 8; ++ct) {
            bf16x8 b = *(const bf16x8*)(pw1 + (((ct * 8 + ks) * 64 + lane) * 8));
            acc[ct] = __builtin_amdgcn_mfma_f32_16x16x32_bf16(a[ks], b, acc[ct], 0, 0, 0);
        }
    }

    // ---- epilogue 1: + dist*w1[256,:] + b1, silu -> sHid (wave-local rows) ----
    float dd[4];
    #pragma unroll
    for (int r = 0; r < 4; ++r) dd[r] = sdist[ebase + we0 + lg * 4 + r];
    #pragma unroll
    for (int ct = 0; ct < 8; ++ct) {
        int col = ct * 16 + lane16;
        float wd = w1f[256 * D + col];
        float b1v = b1[col];
        #pragma unroll
        for (int r = 0; r < 4; ++r) {
            int er = we0 + lg * 4 + r;
            float v = silu_f(acc[ct][r] + dd[r] * wd + b1v);
            int c2 = col >> 3;
            sHid[er][((c2 ^ (er & 7)) * 8) + (col & 7)] = f2b(v);
        }
    }
    // wave-local write->read on sHid; compiler inserts lgkmcnt

    // ---- GEMM2: [64 x 128] @ W2 ----
    f32x4 acc2[8];
    #pragma unroll
    for (int ct = 0; ct < 8; ++ct) acc2[ct] = (f32x4){0.f, 0.f, 0.f, 0.f};
    #pragma unroll
    for (int ks = 0; ks < 4; ++ks) {
        int c = ks * 4 + lg;
        bf16x8 ah = *(const bf16x8*)(&sHid[ar][(c ^ (ar & 7)) * 8]);
        #pragma unroll
        for (int ct = 0; ct < 8; ++ct) {
            bf16x8 b = *(const bf16x8*)(pw2 + (((ct * 4 + ks) * 64 + lane) * 8));
            acc2[ct] = __builtin_amdgcn_mfma_f32_16x16x32_bf16(ah, b, acc2[ct], 0, 0, 0);
        }
    }

    // ---- in-LDS pre-aggregation ----
    __syncthreads();                       // all sHid reads done; safe to overwrite with sAgg
    #pragma unroll
    for (int i = 0; i < 8; ++i)
        ((f32x4*)sAgg)[t + i * 256] = (f32x4){0.f, 0.f, 0.f, 0.f};
    __syncthreads();

    int sl[4];
    #pragma unroll
    for (int r = 0; r < 4; ++r) sl[r] = sSlot[we0 + lg * 4 + r];
    #pragma unroll
    for (int ct = 0; ct < 8; ++ct) {
        int col = ct * 16 + lane16;
        float b2v = b2[col];
        float run = acc2[ct][0] + b2v;
        int cur = sl[0];
        #pragma unroll
        for (int r = 1; r < 4; ++r) {
            float val = acc2[ct][r] + b2v;
            if (sl[r] == cur) run += val;
            else { atomicAdd(&sAgg[cur][col], run); cur = sl[r]; run = val; }
        }
        atomicAdd(&sAgg[cur][col], run);
    }
    __syncthreads();

    // ---- sparse global scatter: one atomic row per distinct node ----
    unsigned long long m = sMask;
    int slot = t >> 2, q = t & 3;
    if (m & (1ull << slot)) {
        int node = sCol[slot];
        float* dst = agg + (size_t)node * D + q * 32;
        #pragma unroll
        for (int i = 0; i < 32; i += 4) {
            f32x4 v = *(f32x4*)&sAgg[slot][q * 32 + i];
            unsafeAtomicAdd(dst + i + 0, v.x);
            unsafeAtomicAdd(dst + i + 1, v.y);
            unsafeAtomicAdd(dst + i + 2, v.z);
            unsafeAtomicAdd(dst + i + 3, v.w);
        }
    }
}

// ---------------- fused node MLP (MFMA) + residual + layernorm ----------------
__global__ __launch_bounds__(256, 3)
void k_node(const float* __restrict__ h, const ushort* __restrict__ hbin,
            const float* __restrict__ agg, const unsigned int* __restrict__ degi,
            const ushort* __restrict__ pw1, const ushort* __restrict__ pw2,
            const float* __restrict__ b1, const float* __restrict__ b2,
            const float* __restrict__ lng, const float* __restrict__ lnb,
            float* __restrict__ hout, ushort* __restrict__ hbout) {
    __shared__ ushort sA[64 * 128];
    __shared__ ushort sHid[64 * 128];

    const int t = threadIdx.x;
    const int nbase = blockIdx.x * 64;

    #pragma unroll
    for (int i = 0; i < 4; ++i) {
        int f = t + i * 256;
        int row = f >> 4, c = f & 15;
        int node = nbase + row; if (node >= NN) node = NN - 1;
        bf16x8 v = *(const bf16x8*)(hbin + (size_t)node * D + c * 8);
        *(bf16x8*)(&sA[row * 128 + ((c ^ (row & 7)) * 8)]) = v;
    }
    __syncthreads();

    const int lane = t & 63;
    const int wv = t >> 6;
    const int we0 = wv * 16;
    const int lane16 = lane & 15;
    const int lg = lane >> 4;
    const int ar = we0 + lane16;

    f32x4 acc[8];
    #pragma unroll
    for (int ct = 0; ct < 8; ++ct) acc[ct] = (f32x4){0.f, 0.f, 0.f, 0.f};
    #pragma unroll
    for (int ks = 0; ks < 4; ++ks) {
        int c = ks * 4 + lg;
        bf16x8 a = *(const bf16x8*)(&sA[ar * 128 + ((c ^ (ar & 7)) * 8)]);
        #pragma unroll
        for (int ct = 0; ct < 8; ++ct) {
            bf16x8 b = *(const bf16x8*)(pw1 + (((ct * 4 + ks) * 64 + lane) * 8));
            acc[ct] = __builtin_amdgcn_mfma_f32_16x16x32_bf16(a, b, acc[ct], 0, 0, 0);
        }
    }

    #pragma unroll
    for (int ct = 0; ct < 8; ++ct) {
        int col = ct * 16 + lane16;
        float b1v = b1[col];
        #pragma unroll
        for (int r = 0; r < 4; ++r) {
            int er = we0 + lg * 4 + r;
            float v = silu_f(acc[ct][r] + b1v);
            int c2 = col >> 3;
            sHid[er * 128 + ((c2 ^ (er & 7)) * 8) + (col & 7)] = f2b(v);
        }
    }

    f32x4 acc2[8];
    #pragma unroll
    for (int ct = 0; ct < 8; ++ct) acc2[ct] = (f32x4){0.f, 0.f, 0.f, 0.f};
    #pragma unroll
    for (int ks = 0; ks < 4; ++ks) {
        int c = ks * 4 + lg;
        bf16x8 a = *(const bf16x8*)(&sHid[ar * 128 + ((c ^ (ar & 7)) * 8)]);
        #pragma unroll
        for (int ct = 0; ct < 8; ++ct) {
            bf16x8 b = *(const bf16x8*)(pw2 + (((ct * 4 + ks) * 64 + lane) * 8));
            acc2[ct] = __builtin_amdgcn_mfma_f32_16x16x32_bf16(a, b, acc2[ct], 0, 0, 0);
        }
    }

    #pragma unroll
    for (int ct = 0; ct < 8; ++ct) {
        int col = ct * 16 + lane16;
        float b2v = b2[col];
        #pragma unroll
        for (int r = 0; r < 4; ++r) {
            int er = we0 + lg * 4 + r;
            int node = nbase + er;
            int ncl = node < NN ? node : NN - 1;
            float invd = 1.0f / fmaxf((float)degi[ncl], 1.0f);
            float y = h[(size_t)ncl * D + col] + acc2[ct][r] + b2v
                    + agg[(size_t)ncl * D + col] * invd;
            acc2[ct][r] = y;
        }
    }

    #pragma unroll
    for (int r = 0; r < 4; ++r) {
        float s = 0.f, s2 = 0.f;
        #pragma unroll
        for (int ct = 0; ct < 8; ++ct) { float y = acc2[ct][r]; s += y; s2 += y * y; }
        #pragma unroll
        for (int off = 1; off < 16; off <<= 1) {
            s  += __shfl_xor(s,  off, 16);
            s2 += __shfl_xor(s2, off, 16);
        }
        float mean = s * (1.0f / D);
        float var  = s2 * (1.0f / D) - mean * mean;
        float rstd = rsqrtf(var + 1e-5f);
        int er = we0 + lg * 4 + r;
        int node = nbase + er;
        if (node < NN) {
            #pragma unroll
            for (int ct = 0; ct < 8; ++ct) {
                int col = ct * 16 + lane16;
                float v = (acc2[ct][r] - mean) * rstd * lng[col] + lnb[col];
                hout[(size_t)node * D + col] = v;
                hbout[(size_t)node * D + col] = f2b(v);
            }
        }
    }
}

extern "C" void kernel_launch(void* const* d_in, const int* in_sizes, int n_in,
                              void* d_out, int out_size, void* d_ws, size_t ws_size,
                              hipStream_t stream) {
    const float* x        = (const float*)d_in[0];
    const float* pos      = (const float*)d_in[1];
    const float* time_emb = (const float*)d_in[2];
    const float* time_w1  = (const float*)d_in[3];
    const float* time_b1  = (const float*)d_in[4];
    const float* time_w2  = (const float*)d_in[5];
    const float* time_b2  = (const float*)d_in[6];
    const float* node_w1  = (const float*)d_in[7];
    const float* node_b1  = (const float*)d_in[8];
    const float* node_w2  = (const float*)d_in[9];
    const float* node_b2  = (const float*)d_in[10];
    const float* edge_w1  = (const float*)d_in[11];
    const float* edge_b1  = (const float*)d_in[12];
    const float* edge_w2  = (const float*)d_in[13];
    const float* edge_b2  = (const float*)d_in[14];
    const float* ln_g     = (const float*)d_in[15];
    const float* ln_b     = (const float*)d_in[16];
    const int*   ei       = (const int*)d_in[17];
    const int*   batch    = (const int*)d_in[18];

    float* h = (float*)d_out;                       // [NN, D]
    float* pos_out = h + (size_t)NN * D;            // [NN, 3]

    char* w = (char*)d_ws;
    float*        tp     = (float*)w;        w += (((size_t)NBATCH * D * 4) + 255) & ~(size_t)255;
    unsigned int* degi   = (unsigned int*)w; w += (((size_t)NN * 4) + 255) & ~(size_t)255;
    unsigned int* part   = (unsigned int*)w; w += 256;
    unsigned int* starts = (unsigned int*)w; w += (((size_t)NN * 4) + 255) & ~(size_t)255;
    int*          srow   = (int*)w;          w += (((size_t)NE * 4) + 255) & ~(size_t)255;
    int*          scol   = (int*)w;          w += (((size_t)NE * 4) + 255) & ~(size_t)255;
    float*        sdist  = (float*)w;        w += (((size_t)NE * 4) + 255) & ~(size_t)255;
    float*        agg    = (float*)w;        w += (((size_t)NN * D * 4) + 255) & ~(size_t)255;
    ushort*       hb     = (ushort*)w;       w += (((size_t)NN * D * 2) + 255) & ~(size_t)255;
    ushort*       pwE1   = (ushort*)w;       w += (((size_t)NLAYERS * 32768 * 2) + 255) & ~(size_t)255;
    ushort*       pwE2   = (ushort*)w;       w += (((size_t)NLAYERS * 16384 * 2) + 255) & ~(size_t)255;
    ushort*       pwN1   = (ushort*)w;       w += (((size_t)NLAYERS * 16384 * 2) + 255) & ~(size_t)255;
    ushort*       pwN2   = (ushort*)w;       w += (((size_t)NLAYERS * 16384 * 2) + 255) & ~(size_t)255;

    hipMemsetAsync(degi, 0, (size_t)NN * 4, stream);
    k_time_mlp<<<NBATCH, D, 0, stream>>>(time_emb, time_w1, time_b1, time_w2, time_b2, tp);
    k_init_h<<<(NN * D) / 256, 256, 0, stream>>>(x, tp, batch, h, hb);
    k_deg<<<NE / 256, 256, 0, stream>>>(ei + NE, degi);

    // exclusive scan + counting sort by target node
    k_scan_a<<<SCANB, 256, 0, stream>>>(degi, part);
    k_scan_b<<<1, 64, 0, stream>>>(part);
    k_scan_c<<<SCANB, 256, 0, stream>>>(degi, part, starts);
    k_sort<<<NE / 256, 256, 0, stream>>>(ei, starts, srow, scol);
    k_dist<<<NE / 256, 256, 0, stream>>>(srow, scol, pos, sdist);

    // weight pre-pack (fragment-major bf16)
    k_pack<<<(NLAYERS * 32768) / 256, 256, 0, stream>>>(edge_w1, pwE1, 3, 257 * 128, 32768);
    k_pack<<<(NLAYERS * 16384) / 256, 256, 0, stream>>>(edge_w2, pwE2, 2, 128 * 128, 16384);
    k_pack<<<(NLAYERS * 16384) / 256, 256, 0, stream>>>(node_w1, pwN1, 2, 128 * 128, 16384);
    k_pack<<<(NLAYERS * 16384) / 256, 256, 0, stream>>>(node_w2, pwN2, 2, 128 * 128, 16384);

    for (int l = 0; l < NLAYERS; ++l) {
        hipMemsetAsync(agg, 0, (size_t)NN * D * 4, stream);
        k_edge<<<NE / 64, 256, 0, stream>>>(hb, srow, scol, sdist,
            pwE1 + (size_t)l * 32768, pwE2 + (size_t)l * 16384,
            edge_w1 + (size_t)l * (2 * D + 1) * D, edge_b1 + (size_t)l * D,
            edge_b2 + (size_t)l * D, agg);
        k_node<<<(NN + 63) / 64, 256, 0, stream>>>(h, hb, agg, degi,
            pwN1 + (size_t)l * 16384, pwN2 + (size_t)l * 16384,
            node_b1 + (size_t)l * D, node_b2 + (size_t)l * D,
            ln_g + (size_t)l * D, ln_b + (size_t)l * D, h, hb);
    }
    hipMemcpyAsync(pos_out, pos, (size_t)NN * 3 * 4, hipMemcpyDeviceToDevice, stream);
}

// Round 4
// 1864.028 us; speedup vs baseline: 1.0479x; 1.0479x over previous
//
#include <hip/hip_runtime.h>
#include <hip/hip_bf16.h>
#include <math.h>

#define NN 50000
#define NE 800000
#define D 128
#define NBATCH 32
#define NLAYERS 3
#define SCANB ((NN + 1023) / 1024)   // 49
#define WSLICE 4096                  // ushorts per 8KB weight K-slice

typedef __attribute__((ext_vector_type(8))) short bf16x8;
typedef __attribute__((ext_vector_type(4))) float f32x4;

__device__ __forceinline__ float silu_f(float x) {
    return x / (1.0f + __expf(-x));
}
__device__ __forceinline__ ushort f2b(float v) {
    __hip_bfloat16 b = __float2bfloat16(v);
    return *(ushort*)&b;
}

// 8KB slice: 2 x 16B chunks per thread, linear LDS dest (wave-uniform base + lane*16)
__device__ __forceinline__ void stage_slice(const ushort* __restrict__ src, ushort* dst, int t) {
    __builtin_amdgcn_global_load_lds(
        (const __attribute__((address_space(1))) unsigned int*)(src + t * 8),
        (__attribute__((address_space(3))) unsigned int*)(dst + t * 8), 16, 0, 0);
    __builtin_amdgcn_global_load_lds(
        (const __attribute__((address_space(1))) unsigned int*)(src + 2048 + t * 8),
        (__attribute__((address_space(3))) unsigned int*)(dst + 2048 + t * 8), 16, 0, 0);
}

// ---------------- time MLP ----------------
__global__ void k_time_mlp(const float* __restrict__ te,
                           const float* __restrict__ w1, const float* __restrict__ b1,
                           const float* __restrict__ w2, const float* __restrict__ b2,
                           float* __restrict__ tp) {
    __shared__ float s_in[D];
    __shared__ float s_hid[D];
    const int b = blockIdx.x;
    const int j = threadIdx.x;
    s_in[j] = te[b * D + j];
    __syncthreads();
    float acc = b1[j];
    for (int k = 0; k < D; ++k) acc = fmaf(s_in[k], w1[k * D + j], acc);
    s_hid[j] = silu_f(acc);
    __syncthreads();
    float acc2 = b2[j];
    for (int k = 0; k < D; ++k) acc2 = fmaf(s_hid[k], w2[k * D + j], acc2);
    tp[b * D + j] = acc2;
}

// ---------------- h = x + tp[batch]; also h_bf16 ----------------
__global__ void k_init_h(const float* __restrict__ x, const float* __restrict__ tp,
                         const int* __restrict__ batch, float* __restrict__ h,
                         ushort* __restrict__ hb) {
    int idx = blockIdx.x * 256 + threadIdx.x;
    int n = idx >> 7, c = idx & 127;
    float v = x[idx] + tp[batch[n] * D + c];
    h[idx] = v;
    hb[idx] = f2b(v);
}

// ---------------- integer degree ----------------
__global__ void k_deg(const int* __restrict__ col, unsigned int* __restrict__ deg) {
    int e = blockIdx.x * 256 + threadIdx.x;
    atomicAdd(&deg[col[e]], 1u);
}

// ---------------- exclusive scan over deg ----------------
__global__ void k_scan_a(const unsigned int* __restrict__ deg, unsigned int* __restrict__ part) {
    __shared__ unsigned int sl[256];
    int b = blockIdx.x, t = threadIdx.x;
    unsigned int s = 0;
    #pragma unroll
    for (int i = 0; i < 4; ++i) {
        int idx = b * 1024 + t * 4 + i;
        if (idx < NN) s += deg[idx];
    }
    sl[t] = s; __syncthreads();
    for (int off = 128; off; off >>= 1) {
        if (t < off) sl[t] += sl[t + off];
        __syncthreads();
    }
    if (t == 0) part[b] = sl[0];
}
__global__ void k_scan_b(unsigned int* __restrict__ part) {
    __shared__ unsigned int sp[64];
    int t = threadIdx.x;
    sp[t] = (t < SCANB) ? part[t] : 0u;
    __syncthreads();
    if (t == 0) {
        unsigned int run = 0;
        for (int i = 0; i < SCANB; ++i) { unsigned int v = sp[i]; sp[i] = run; run += v; }
    }
    __syncthreads();
    if (t < SCANB) part[t] = sp[t];
}
__global__ void k_scan_c(const unsigned int* __restrict__ deg, const unsigned int* __restrict__ part,
                         unsigned int* __restrict__ starts) {
    __shared__ unsigned int sl[256];
    int b = blockIdx.x, t = threadIdx.x;
    unsigned int v4[4]; unsigned int s = 0;
    #pragma unroll
    for (int i = 0; i < 4; ++i) {
        int idx = b * 1024 + t * 4 + i;
        v4[i] = (idx < NN) ? deg[idx] : 0u;
        s += v4[i];
    }
    sl[t] = s; __syncthreads();
    if (t == 0) {
        unsigned int run = 0;
        for (int i = 0; i < 256; ++i) { unsigned int x = sl[i]; sl[i] = run; run += x; }
    }
    __syncthreads();
    unsigned int off = part[b] + sl[t];
    #pragma unroll
    for (int i = 0; i < 4; ++i) {
        int idx = b * 1024 + t * 4 + i;
        if (idx < NN) { starts[idx] = off; off += v4[i]; }
    }
}

// ---------------- counting-sort placement ----------------
__global__ void k_sort(const int* __restrict__ ei, unsigned int* __restrict__ cursor,
                       int* __restrict__ srow, int* __restrict__ scol) {
    int e = blockIdx.x * 256 + threadIdx.x;
    int r = ei[e], c = ei[NE + e];
    unsigned int p = atomicAdd(&cursor[c], 1u);
    srow[p] = r; scol[p] = c;
}

// ---------------- per-edge distance (sorted order) ----------------
__global__ void k_dist(const int* __restrict__ srow, const int* __restrict__ scol,
                       const float* __restrict__ pos, float* __restrict__ sdist) {
    int e = blockIdx.x * 256 + threadIdx.x;
    int r = srow[e], c = scol[e];
    float dx = pos[r * 3 + 0] - pos[c * 3 + 0];
    float dy = pos[r * 3 + 1] - pos[c * 3 + 1];
    float dz = pos[r * 3 + 2] - pos[c * 3 + 2];
    sdist[e] = sqrtf(dx * dx + dy * dy + dz * dz);
}

// ---------------- weight pre-pack: slice-major bf16 [ks][ct][lane][8] ----------------
__global__ void k_pack(const float* __restrict__ W, ushort* __restrict__ out,
                       int layerStrideW, int totalPerLayer) {
    int t = blockIdx.x * 256 + threadIdx.x;
    int l = t / totalPerLayer;
    int r = t - l * totalPerLayer;
    int j = r & 7;
    int lane = (r >> 3) & 63;
    int ct = (r >> 9) & 7;
    int ks = r >> 12;
    int k = ks * 32 + ((lane >> 4) << 3) + j;
    int n = ct * 16 + (lane & 15);
    out[t] = f2b(W[(size_t)l * layerStrideW + k * 128 + n]);
}

// ---------------- fused edge MLP: LDS-streamed weights + MFMA + pre-agg scatter ----------------
// 256 threads = 4 waves; 64 sorted edges; 12 K-slices double-buffered through LDS.
__global__ __launch_bounds__(256, 4)
void k_edge(const ushort* __restrict__ hb,
            const int* __restrict__ srow, const int* __restrict__ scol,
            const float* __restrict__ sdist,
            const ushort* __restrict__ pw1, const ushort* __restrict__ pw2,
            const float* __restrict__ w1f, const float* __restrict__ b1,
            const float* __restrict__ b2,
            float* __restrict__ agg) {
    __shared__ float sAgg[64][128];                       // 32 KB total
    __shared__ int sCol[64];
    __shared__ int sSlot[64];
    __shared__ unsigned long long sMask;
    __shared__ float sDist[64];

    ushort* sBu   = (ushort*)&sAgg[0][0];                 // 16 KB: sB[2][4096]
    ushort* sHidu = (ushort*)&sAgg[32][0];                // 16 KB: [64][128] swizzled

    const int t = threadIdx.x;
    const int ebase = blockIdx.x * 64;

    if (t < 64) {   // wave 0
        int c = scol[ebase + t];
        sCol[t] = c;
        sDist[t] = sdist[ebase + t];
        bool flag = (t == 0) || (scol[ebase + t - 1] != c);
        unsigned long long m = __ballot(flag);
        sSlot[t] = t - __builtin_clzll(m << (63 - t));
        if (t == 0) sMask = m;
    }
    __syncthreads();

    const int lane = t & 63;
    const int wv = t >> 6;
    const int we0 = wv * 16;
    const int lane16 = lane & 15;
    const int lg = lane >> 4;
    const int ar = we0 + lane16;

    // A gather: global -> registers (h[col] chunks 0-3, h[row] chunks 4-7)
    const int nc = sCol[ar];
    const int nr = srow[ebase + ar];
    const ushort* pc = hb + (size_t)nc * D;
    const ushort* pr = hb + (size_t)nr * D;
    bf16x8 a[8];
    #pragma unroll
    for (int ks = 0; ks < 4; ++ks) a[ks]     = *(const bf16x8*)(pc + (ks * 4 + lg) * 8);
    #pragma unroll
    for (int ks = 0; ks < 4; ++ks) a[4 + ks] = *(const bf16x8*)(pr + (ks * 4 + lg) * 8);

    stage_slice(pw1, sBu, t);     // slice 0
    __syncthreads();              // drains vmcnt: a[] + sB[0] ready

    f32x4 acc[8], acc2[8];
    #pragma unroll
    for (int ct = 0; ct < 8; ++ct) acc[ct] = (f32x4){0.f, 0.f, 0.f, 0.f};

    int cur = 0;
    #pragma unroll
    for (int s = 0; s < 12; ++s) {
        if (s < 11) {
            const ushort* nsrc = (s + 1 < 8) ? (pw1 + (s + 1) * WSLICE)
                                             : (pw2 + (s + 1 - 8) * WSLICE);
            stage_slice(nsrc, sBu + (cur ^ 1) * WSLICE, t);
        }
        if (s == 8) {
            // epilogue 1: + dist*w1[256,:] + b1, silu -> sHid (wave-local rows)
            float dd[4];
            #pragma unroll
            for (int r = 0; r < 4; ++r) dd[r] = sDist[we0 + lg * 4 + r];
            #pragma unroll
            for (int ct = 0; ct < 8; ++ct) {
                int col = ct * 16 + lane16;
                float wd = w1f[256 * D + col];
                float b1v = b1[col];
                #pragma unroll
                for (int r = 0; r < 4; ++r) {
                    int er = we0 + lg * 4 + r;
                    float v = silu_f(acc[ct][r] + dd[r] * wd + b1v);
                    int c2 = col >> 3;
                    sHidu[er * 128 + ((c2 ^ (er & 7)) * 8) + (col & 7)] = f2b(v);
                }
            }
            #pragma unroll
            for (int ct = 0; ct < 8; ++ct) acc2[ct] = (f32x4){0.f, 0.f, 0.f, 0.f};
        }
        if (s < 8) {
            #pragma unroll
            for (int ct = 0; ct < 8; ++ct) {
                bf16x8 b = *(const bf16x8*)(sBu + cur * WSLICE + ct * 512 + lane * 8);
                acc[ct] = __builtin_amdgcn_mfma_f32_16x16x32_bf16(a[s], b, acc[ct], 0, 0, 0);
            }
        } else {
            int c = (s - 8) * 4 + lg;
            bf16x8 ah = *(const bf16x8*)(sHidu + ar * 128 + ((c ^ (ar & 7)) * 8));
            #pragma unroll
            for (int ct = 0; ct < 8; ++ct) {
                bf16x8 b = *(const bf16x8*)(sBu + cur * WSLICE + ct * 512 + lane * 8);
                acc2[ct] = __builtin_amdgcn_mfma_f32_16x16x32_bf16(ah, b, acc2[ct], 0, 0, 0);
            }
        }
        __syncthreads();
        cur ^= 1;
    }

    // ---- in-LDS pre-aggregation (sAgg aliases sB+sHid; both dead now) ----
    #pragma unroll
    for (int i = 0; i < 8; ++i)
        ((f32x4*)sAgg)[t + i * 256] = (f32x4){0.f, 0.f, 0.f, 0.f};
    __syncthreads();

    int sl[4];
    #pragma unroll
    for (int r = 0; r < 4; ++r) sl[r] = sSlot[we0 + lg * 4 + r];
    #pragma unroll
    for (int ct = 0; ct < 8; ++ct) {
        int col = ct * 16 + lane16;
        float b2v = b2[col];
        float run = acc2[ct][0] + b2v;
        int curslot = sl[0];
        #pragma unroll
        for (int r = 1; r < 4; ++r) {
            float val = acc2[ct][r] + b2v;
            if (sl[r] == curslot) run += val;
            else { atomicAdd(&sAgg[curslot][col], run); curslot = sl[r]; run = val; }
        }
        atomicAdd(&sAgg[curslot][col], run);
    }
    __syncthreads();

    // ---- sparse global scatter: one atomic row per distinct target node ----
    unsigned long long m = sMask;
    int slot = t >> 2, q = t & 3;
    if (m & (1ull << slot)) {
        int node = sCol[slot];
        float* dst = agg + (size_t)node * D + q * 32;
        #pragma unroll
        for (int i = 0; i < 32; i += 4) {
            f32x4 v = *(f32x4*)&sAgg[slot][q * 32 + i];
            unsafeAtomicAdd(dst + i + 0, v.x);
            unsafeAtomicAdd(dst + i + 1, v.y);
            unsafeAtomicAdd(dst + i + 2, v.z);
            unsafeAtomicAdd(dst + i + 3, v.w);
        }
    }
}

// ---------------- fused node MLP: LDS-streamed weights + residual + layernorm ----------------
__global__ __launch_bounds__(256, 4)
void k_node(const float* __restrict__ h, const ushort* __restrict__ hbin,
            const float* __restrict__ agg, const unsigned int* __restrict__ degi,
            const ushort* __restrict__ pw1, const ushort* __restrict__ pw2,
            const float* __restrict__ b1, const float* __restrict__ b2,
            const float* __restrict__ lng, const float* __restrict__ lnb,
            float* __restrict__ hout, ushort* __restrict__ hbout) {
    __shared__ ushort sBu[2 * WSLICE];    // 16 KB
    __shared__ ushort sHidu[64 * 128];    // 16 KB

    const int t = threadIdx.x;
    const int nbase = blockIdx.x * 64;

    const int lane = t & 63;
    const int wv = t >> 6;
    const int we0 = wv * 16;
    const int lane16 = lane & 15;
    const int lg = lane >> 4;
    const int ar = we0 + lane16;
    const int nodeA = nbase + ar;
    const int nclA = nodeA < NN ? nodeA : NN - 1;

    bf16x8 a[4];
    #pragma unroll
    for (int ks = 0; ks < 4; ++ks)
        a[ks] = *(const bf16x8*)(hbin + (size_t)nclA * D + (ks * 4 + lg) * 8);

    stage_slice(pw1, sBu, t);
    __syncthreads();

    f32x4 acc[8], acc2[8];
    #pragma unroll
    for (int ct = 0; ct < 8; ++ct) acc[ct] = (f32x4){0.f, 0.f, 0.f, 0.f};

    int cur = 0;
    #pragma unroll
    for (int s = 0; s < 8; ++s) {
        if (s < 7) {
            const ushort* nsrc = (s + 1 < 4) ? (pw1 + (s + 1) * WSLICE)
                                             : (pw2 + (s + 1 - 4) * WSLICE);
            stage_slice(nsrc, sBu + (cur ^ 1) * WSLICE, t);
        }
        if (s == 4) {
            #pragma unroll
            for (int ct = 0; ct < 8; ++ct) {
                int col = ct * 16 + lane16;
                float b1v = b1[col];
                #pragma unroll
                for (int r = 0; r < 4; ++r) {
                    int er = we0 + lg * 4 + r;
                    float v = silu_f(acc[ct][r] + b1v);
                    int c2 = col >> 3;
                    sHidu[er * 128 + ((c2 ^ (er & 7)) * 8) + (col & 7)] = f2b(v);
                }
            }
            #pragma unroll
            for (int ct = 0; ct < 8; ++ct) acc2[ct] = (f32x4){0.f, 0.f, 0.f, 0.f};
        }
        if (s < 4) {
            #pragma unroll
            for (int ct = 0; ct < 8; ++ct) {
                bf16x8 b = *(const bf16x8*)(sBu + cur * WSLICE + ct * 512 + lane * 8);
                acc[ct] = __builtin_amdgcn_mfma_f32_16x16x32_bf16(a[s], b, acc[ct], 0, 0, 0);
            }
        } else {
            int c = (s - 4) * 4 + lg;
            bf16x8 ah = *(const bf16x8*)(sHidu + ar * 128 + ((c ^ (ar & 7)) * 8));
            #pragma unroll
            for (int ct = 0; ct < 8; ++ct) {
                bf16x8 b = *(const bf16x8*)(sBu + cur * WSLICE + ct * 512 + lane * 8);
                acc2[ct] = __builtin_amdgcn_mfma_f32_16x16x32_bf16(ah, b, acc2[ct], 0, 0, 0);
            }
        }
        __syncthreads();
        cur ^= 1;
    }

    // y = h + nodeMLP(h) + b2 + agg/deg
    #pragma unroll
    for (int ct = 0; ct < 8; ++ct) {
        int col = ct * 16 + lane16;
        float b2v = b2[col];
        #pragma unroll
        for (int r = 0; r < 4; ++r) {
            int er = we0 + lg * 4 + r;
            int node = nbase + er;
            int ncl = node < NN ? node : NN - 1;
            float invd = 1.0f / fmaxf((float)degi[ncl], 1.0f);
            float y = h[(size_t)ncl * D + col] + acc2[ct][r] + b2v
                    + agg[(size_t)ncl * D + col] * invd;
            acc2[ct][r] = y;
        }
    }

    #pragma unroll
    for (int r = 0; r < 4; ++r) {
        float s = 0.f, s2 = 0.f;
        #pragma unroll
        for (int ct = 0; ct < 8; ++ct) { float y = acc2[ct][r]; s += y; s2 += y * y; }
        #pragma unroll
        for (int off = 1; off < 16; off <<= 1) {
            s  += __shfl_xor(s,  off, 16);
            s2 += __shfl_xor(s2, off, 16);
        }
        float mean = s * (1.0f / D);
        float var  = s2 * (1.0f / D) - mean * mean;
        float rstd = rsqrtf(var + 1e-5f);
        int er = we0 + lg * 4 + r;
        int node = nbase + er;
        if (node < NN) {
            #pragma unroll
            for (int ct = 0; ct < 8; ++ct) {
                int col = ct * 16 + lane16;
                float v = (acc2[ct][r] - mean) * rstd * lng[col] + lnb[col];
                hout[(size_t)node * D + col] = v;
                hbout[(size_t)node * D + col] = f2b(v);
            }
        }
    }
}

extern "C" void kernel_launch(void* const* d_in, const int* in_sizes, int n_in,
                              void* d_out, int out_size, void* d_ws, size_t ws_size,
                              hipStream_t stream) {
    const float* x        = (const float*)d_in[0];
    const float* pos      = (const float*)d_in[1];
    const float* time_emb = (const float*)d_in[2];
    const float* time_w1  = (const float*)d_in[3];
    const float* time_b1  = (const float*)d_in[4];
    const float* time_w2  = (const float*)d_in[5];
    const float* time_b2  = (const float*)d_in[6];
    const float* node_w1  = (const float*)d_in[7];
    const float* node_b1  = (const float*)d_in[8];
    const float* node_w2  = (const float*)d_in[9];
    const float* node_b2  = (const float*)d_in[10];
    const float* edge_w1  = (const float*)d_in[11];
    const float* edge_b1  = (const float*)d_in[12];
    const float* edge_w2  = (const float*)d_in[13];
    const float* edge_b2  = (const float*)d_in[14];
    const float* ln_g     = (const float*)d_in[15];
    const float* ln_b     = (const float*)d_in[16];
    const int*   ei       = (const int*)d_in[17];
    const int*   batch    = (const int*)d_in[18];

    float* h = (float*)d_out;                       // [NN, D]
    float* pos_out = h + (size_t)NN * D;            // [NN, 3]

    char* w = (char*)d_ws;
    float*        tp     = (float*)w;        w += (((size_t)NBATCH * D * 4) + 255) & ~(size_t)255;
    unsigned int* degi   = (unsigned int*)w; w += (((size_t)NN * 4) + 255) & ~(size_t)255;
    unsigned int* part   = (unsigned int*)w; w += 256;
    unsigned int* starts = (unsigned int*)w; w += (((size_t)NN * 4) + 255) & ~(size_t)255;
    int*          srow   = (int*)w;          w += (((size_t)NE * 4) + 255) & ~(size_t)255;
    int*          scol   = (int*)w;          w += (((size_t)NE * 4) + 255) & ~(size_t)255;
    float*        sdist  = (float*)w;        w += (((size_t)NE * 4) + 255) & ~(size_t)255;
    float*        agg    = (float*)w;        w += (((size_t)NN * D * 4) + 255) & ~(size_t)255;
    ushort*       hb     = (ushort*)w;       w += (((size_t)NN * D * 2) + 255) & ~(size_t)255;
    ushort*       pwE1   = (ushort*)w;       w += (((size_t)NLAYERS * 32768 * 2) + 255) & ~(size_t)255;
    ushort*       pwE2   = (ushort*)w;       w += (((size_t)NLAYERS * 16384 * 2) + 255) & ~(size_t)255;
    ushort*       pwN1   = (ushort*)w;       w += (((size_t)NLAYERS * 16384 * 2) + 255) & ~(size_t)255;
    ushort*       pwN2   = (ushort*)w;       w += (((size_t)NLAYERS * 16384 * 2) + 255) & ~(size_t)255;

    hipMemsetAsync(degi, 0, (size_t)NN * 4, stream);
    k_time_mlp<<<NBATCH, D, 0, stream>>>(time_emb, time_w1, time_b1, time_w2, time_b2, tp);
    k_init_h<<<(NN * D) / 256, 256, 0, stream>>>(x, tp, batch, h, hb);
    k_deg<<<NE / 256, 256, 0, stream>>>(ei + NE, degi);

    k_scan_a<<<SCANB, 256, 0, stream>>>(degi, part);
    k_scan_b<<<1, 64, 0, stream>>>(part);
    k_scan_c<<<SCANB, 256, 0, stream>>>(degi, part, starts);
    k_sort<<<NE / 256, 256, 0, stream>>>(ei, starts, srow, scol);
    k_dist<<<NE / 256, 256, 0, stream>>>(srow, scol, pos, sdist);

    // weight pre-pack (slice-major fragment layout)
    k_pack<<<(NLAYERS * 32768) / 256, 256, 0, stream>>>(edge_w1, pwE1, 257 * 128, 32768);
    k_pack<<<(NLAYERS * 16384) / 256, 256, 0, stream>>>(edge_w2, pwE2, 128 * 128, 16384);
    k_pack<<<(NLAYERS * 16384) / 256, 256, 0, stream>>>(node_w1, pwN1, 128 * 128, 16384);
    k_pack<<<(NLAYERS * 16384) / 256, 256, 0, stream>>>(node_w2, pwN2, 128 * 128, 16384);

    for (int l = 0; l < NLAYERS; ++l) {
        hipMemsetAsync(agg, 0, (size_t)NN * D * 4, stream);
        k_edge<<<NE / 64, 256, 0, stream>>>(hb, srow, scol, sdist,
            pwE1 + (size_t)l * 32768, pwE2 + (size_t)l * 16384,
            edge_w1 + (size_t)l * (2 * D + 1) * D, edge_b1 + (size_t)l * D,
            edge_b2 + (size_t)l * D, agg);
        k_node<<<(NN + 63) / 64, 256, 0, stream>>>(h, hb, agg, degi,
            pwN1 + (size_t)l * 16384, pwN2 + (size_t)l * 16384,
            node_b1 + (size_t)l * D, node_b2 + (size_t)l * D,
            ln_g + (size_t)l * D, ln_b + (size_t)l * D, h, hb);
    }
    hipMemcpyAsync(pos_out, pos, (size_t)NN * 3 * 4, hipMemcpyDeviceToDevice, stream);
}

// Round 5
// 1249.151 us; speedup vs baseline: 1.5637x; 1.4922x over previous
//
#include <hip/hip_runtime.h>
#include <hip/hip_bf16.h>
#include <math.h>

#define NN 50000
#define NE 800000
#define D 128
#define NBATCH 32
#define NLAYERS 3
#define SCANB ((NN + 1023) / 1024)   // 49
#define WSLICE 4096                  // ushorts per 8KB weight K-slice
#define NTILES (NE / 16)             // 50000
#define NWAVES 2048                  // 256 blocks x 8 waves
#define TPW ((NTILES + NWAVES - 1) / NWAVES)   // 25

typedef __attribute__((ext_vector_type(8))) short bf16x8;
typedef __attribute__((ext_vector_type(4))) float f32x4;

__device__ __forceinline__ float silu_f(float x) {
    return x / (1.0f + __expf(-x));
}
__device__ __forceinline__ ushort f2b(float v) {
    __hip_bfloat16 b = __float2bfloat16(v);
    return *(ushort*)&b;
}

// ---------------- time MLP ----------------
__global__ void k_time_mlp(const float* __restrict__ te,
                           const float* __restrict__ w1, const float* __restrict__ b1,
                           const float* __restrict__ w2, const float* __restrict__ b2,
                           float* __restrict__ tp) {
    __shared__ float s_in[D];
    __shared__ float s_hid[D];
    const int b = blockIdx.x;
    const int j = threadIdx.x;
    s_in[j] = te[b * D + j];
    __syncthreads();
    float acc = b1[j];
    for (int k = 0; k < D; ++k) acc = fmaf(s_in[k], w1[k * D + j], acc);
    s_hid[j] = silu_f(acc);
    __syncthreads();
    float acc2 = b2[j];
    for (int k = 0; k < D; ++k) acc2 = fmaf(s_hid[k], w2[k * D + j], acc2);
    tp[b * D + j] = acc2;
}

// ---------------- h = x + tp[batch]; also h_bf16 ----------------
__global__ void k_init_h(const float* __restrict__ x, const float* __restrict__ tp,
                         const int* __restrict__ batch, float* __restrict__ h,
                         ushort* __restrict__ hb) {
    int idx = blockIdx.x * 256 + threadIdx.x;
    int n = idx >> 7, c = idx & 127;
    float v = x[idx] + tp[batch[n] * D + c];
    h[idx] = v;
    hb[idx] = f2b(v);
}

// ---------------- integer degree ----------------
__global__ void k_deg(const int* __restrict__ col, unsigned int* __restrict__ deg) {
    int e = blockIdx.x * 256 + threadIdx.x;
    atomicAdd(&deg[col[e]], 1u);
}

// ---------------- exclusive scan over deg ----------------
__global__ void k_scan_a(const unsigned int* __restrict__ deg, unsigned int* __restrict__ part) {
    __shared__ unsigned int sl[256];
    int b = blockIdx.x, t = threadIdx.x;
    unsigned int s = 0;
    #pragma unroll
    for (int i = 0; i < 4; ++i) {
        int idx = b * 1024 + t * 4 + i;
        if (idx < NN) s += deg[idx];
    }
    sl[t] = s; __syncthreads();
    for (int off = 128; off; off >>= 1) {
        if (t < off) sl[t] += sl[t + off];
        __syncthreads();
    }
    if (t == 0) part[b] = sl[0];
}
__global__ void k_scan_b(unsigned int* __restrict__ part) {
    __shared__ unsigned int sp[64];
    int t = threadIdx.x;
    sp[t] = (t < SCANB) ? part[t] : 0u;
    __syncthreads();
    if (t == 0) {
        unsigned int run = 0;
        for (int i = 0; i < SCANB; ++i) { unsigned int v = sp[i]; sp[i] = run; run += v; }
    }
    __syncthreads();
    if (t < SCANB) part[t] = sp[t];
}
__global__ void k_scan_c(const unsigned int* __restrict__ deg, const unsigned int* __restrict__ part,
                         unsigned int* __restrict__ starts) {
    __shared__ unsigned int sl[256];
    int b = blockIdx.x, t = threadIdx.x;
    unsigned int v4[4]; unsigned int s = 0;
    #pragma unroll
    for (int i = 0; i < 4; ++i) {
        int idx = b * 1024 + t * 4 + i;
        v4[i] = (idx < NN) ? deg[idx] : 0u;
        s += v4[i];
    }
    sl[t] = s; __syncthreads();
    if (t == 0) {
        unsigned int run = 0;
        for (int i = 0; i < 256; ++i) { unsigned int x = sl[i]; sl[i] = run; run += x; }
    }
    __syncthreads();
    unsigned int off = part[b] + sl[t];
    #pragma unroll
    for (int i = 0; i < 4; ++i) {
        int idx = b * 1024 + t * 4 + i;
        if (idx < NN) { starts[idx] = off; off += v4[i]; }
    }
}

// ---------------- counting-sort placement ----------------
__global__ void k_sort(const int* __restrict__ ei, unsigned int* __restrict__ cursor,
                       int* __restrict__ srow, int* __restrict__ scol) {
    int e = blockIdx.x * 256 + threadIdx.x;
    int r = ei[e], c = ei[NE + e];
    unsigned int p = atomicAdd(&cursor[c], 1u);
    srow[p] = r; scol[p] = c;
}

// ---------------- per-edge distance (sorted order) ----------------
__global__ void k_dist(const int* __restrict__ srow, const int* __restrict__ scol,
                       const float* __restrict__ pos, float* __restrict__ sdist) {
    int e = blockIdx.x * 256 + threadIdx.x;
    int r = srow[e], c = scol[e];
    float dx = pos[r * 3 + 0] - pos[c * 3 + 0];
    float dy = pos[r * 3 + 1] - pos[c * 3 + 1];
    float dz = pos[r * 3 + 2] - pos[c * 3 + 2];
    sdist[e] = sqrtf(dx * dx + dy * dy + dz * dz);
}

// ---------------- weight pre-pack: slice-major bf16 [ks][ct][lane][8] ----------------
__global__ void k_pack(const float* __restrict__ W, ushort* __restrict__ out,
                       int layerStrideW, int totalPerLayer) {
    int t = blockIdx.x * 256 + threadIdx.x;
    int l = t / totalPerLayer;
    int r = t - l * totalPerLayer;
    int j = r & 7;
    int lane = (r >> 3) & 63;
    int ct = (r >> 9) & 7;
    int ks = r >> 12;
    int k = ks * 32 + ((lane >> 4) << 3) + j;
    int n = ct * 16 + (lane & 15);
    out[t] = f2b(W[(size_t)l * layerStrideW + k * 128 + n]);
}

// ---------------- fused edge MLP: resident LDS weights, per-wave tiles, no loop barriers ----------------
// 512 threads = 8 waves; each wave independently processes TPW tiles of 16 sorted edges.
__global__ __launch_bounds__(512, 2)
void k_edge(const ushort* __restrict__ hb,
            const int* __restrict__ srow, const int* __restrict__ scol,
            const float* __restrict__ sdist,
            const ushort* __restrict__ pw1, const ushort* __restrict__ pw2,
            const float* __restrict__ w1f, const float* __restrict__ b1,
            const float* __restrict__ b2,
            float* __restrict__ agg) {
    __shared__ ushort sW1[32768];        // 64 KB
    __shared__ ushort sW2[16384];        // 32 KB
    __shared__ ushort sHid[8][2048];     // 32 KB, per-wave [16][128] swizzled

    const int t = threadIdx.x;

    // ---- stage ALL weights once (one barrier for the whole kernel) ----
    #pragma unroll
    for (int j = 0; j < 8; ++j)
        __builtin_amdgcn_global_load_lds(
            (const __attribute__((address_space(1))) unsigned int*)(pw1 + (j * 512 + t) * 8),
            (__attribute__((address_space(3))) unsigned int*)(sW1 + (j * 512 + t) * 8), 16, 0, 0);
    #pragma unroll
    for (int j = 0; j < 4; ++j)
        __builtin_amdgcn_global_load_lds(
            (const __attribute__((address_space(1))) unsigned int*)(pw2 + (j * 512 + t) * 8),
            (__attribute__((address_space(3))) unsigned int*)(sW2 + (j * 512 + t) * 8), 16, 0, 0);
    __syncthreads();

    const int lane = t & 63;
    const int wv = t >> 6;
    const int lane16 = lane & 15;
    const int lg = lane >> 4;

    int tile = (blockIdx.x * 8 + wv) * TPW;
    int tend = tile + TPW; if (tend > NTILES) tend = NTILES;
    if (tile >= tend) return;

    // ---- prologue: indices + A rows + dist + merge-cols for tile 0 ----
    int base = tile * 16;
    int ncA = scol[base + lane16];
    int nrA = srow[base + lane16];
    float ddA[4]; int cmA[4];
    #pragma unroll
    for (int r = 0; r < 4; ++r) {
        ddA[r] = sdist[base + lg * 4 + r];
        cmA[r] = scol[base + lg * 4 + r];
    }
    bf16x8 aC[8];
    {
        const ushort* pc = hb + (size_t)ncA * D;
        const ushort* pr = hb + (size_t)nrA * D;
        #pragma unroll
        for (int ks = 0; ks < 4; ++ks) aC[ks]     = *(const bf16x8*)(pc + (ks * 4 + lg) * 8);
        #pragma unroll
        for (int ks = 0; ks < 4; ++ks) aC[4 + ks] = *(const bf16x8*)(pr + (ks * 4 + lg) * 8);
    }

    ushort* myHid = &sHid[wv][0];

    for (; tile < tend; ++tile) {
        const bool more = (tile + 1 < tend);

        // ---- issue index/dist/col loads for tile i+1 (latency hidden under GEMM1) ----
        int ncN = 0, nrN = 0; float ddN[4]; int cmN[4];
        if (more) {
            int nb = (tile + 1) * 16;
            ncN = scol[nb + lane16];
            nrN = srow[nb + lane16];
            #pragma unroll
            for (int r = 0; r < 4; ++r) {
                ddN[r] = sdist[nb + lg * 4 + r];
                cmN[r] = scol[nb + lg * 4 + r];
            }
        }

        // ---- GEMM1: [16 x 256] @ W1 (B from resident LDS) ----
        f32x4 acc[8];
        #pragma unroll
        for (int ct = 0; ct < 8; ++ct) acc[ct] = (f32x4){0.f, 0.f, 0.f, 0.f};
        #pragma unroll
        for (int ks = 0; ks < 8; ++ks) {
            #pragma unroll
            for (int ct = 0; ct < 8; ++ct) {
                bf16x8 b = *(const bf16x8*)(sW1 + ((ks * 8 + ct) * 64 + lane) * 8);
                acc[ct] = __builtin_amdgcn_mfma_f32_16x16x32_bf16(aC[ks], b, acc[ct], 0, 0, 0);
            }
        }

        // ---- epilogue 1: + dist*w1[256,:] + b1, silu -> my wave's sHid region ----
        #pragma unroll
        for (int ct = 0; ct < 8; ++ct) {
            int col = ct * 16 + lane16;
            float wd = w1f[256 * D + col];
            float b1v = b1[col];
            #pragma unroll
            for (int r = 0; r < 4; ++r) {
                int er = lg * 4 + r;
                float v = silu_f(acc[ct][r] + ddA[r] * wd + b1v);
                int c2 = col >> 3;
                myHid[er * 128 + ((c2 ^ (er & 7)) * 8) + (col & 7)] = f2b(v);
            }
        }

        // ---- issue A-row loads for tile i+1 (indices have arrived; hidden under GEMM2) ----
        bf16x8 aN[8];
        if (more) {
            const ushort* pc = hb + (size_t)ncN * D;
            const ushort* pr = hb + (size_t)nrN * D;
            #pragma unroll
            for (int ks = 0; ks < 4; ++ks) aN[ks]     = *(const bf16x8*)(pc + (ks * 4 + lg) * 8);
            #pragma unroll
            for (int ks = 0; ks < 4; ++ks) aN[4 + ks] = *(const bf16x8*)(pr + (ks * 4 + lg) * 8);
        }

        // ---- GEMM2: [16 x 128] @ W2 (A from wave-local sHid, B from resident LDS) ----
        f32x4 acc2[8];
        #pragma unroll
        for (int ct = 0; ct < 8; ++ct) acc2[ct] = (f32x4){0.f, 0.f, 0.f, 0.f};
        #pragma unroll
        for (int ks = 0; ks < 4; ++ks) {
            int c = ks * 4 + lg;
            bf16x8 ah = *(const bf16x8*)(myHid + lane16 * 128 + ((c ^ (lane16 & 7)) * 8));
            #pragma unroll
            for (int ct = 0; ct < 8; ++ct) {
                bf16x8 b = *(const bf16x8*)(sW2 + ((ks * 8 + ct) * 64 + lane) * 8);
                acc2[ct] = __builtin_amdgcn_mfma_f32_16x16x32_bf16(ah, b, acc2[ct], 0, 0, 0);
            }
        }

        // ---- scatter: run-merge along sorted rows, direct global atomics ----
        #pragma unroll
        for (int ct = 0; ct < 8; ++ct) {
            int col = ct * 16 + lane16;
            float b2v = b2[col];
            float run = acc2[ct][0] + b2v;
            int cur = cmA[0];
            #pragma unroll
            for (int r = 1; r < 4; ++r) {
                float val = acc2[ct][r] + b2v;
                if (cmA[r] == cur) run += val;
                else { unsafeAtomicAdd(agg + (size_t)cur * D + col, run); cur = cmA[r]; run = val; }
            }
            unsafeAtomicAdd(agg + (size_t)cur * D + col, run);
        }

        // ---- rotate pipeline registers ----
        if (more) {
            #pragma unroll
            for (int ks = 0; ks < 8; ++ks) aC[ks] = aN[ks];
            ncA = ncN; nrA = nrN;
            #pragma unroll
            for (int r = 0; r < 4; ++r) { ddA[r] = ddN[r]; cmA[r] = cmN[r]; }
        }
    }
}

// ---------------- fused node MLP: LDS-streamed weights + residual + layernorm ----------------
__global__ __launch_bounds__(256, 4)
void k_node(const float* __restrict__ h, const ushort* __restrict__ hbin,
            const float* __restrict__ agg, const unsigned int* __restrict__ degi,
            const ushort* __restrict__ pw1, const ushort* __restrict__ pw2,
            const float* __restrict__ b1, const float* __restrict__ b2,
            const float* __restrict__ lng, const float* __restrict__ lnb,
            float* __restrict__ hout, ushort* __restrict__ hbout) {
    __shared__ ushort sBu[2 * WSLICE];    // 16 KB
    __shared__ ushort sHidu[64 * 128];    // 16 KB

    const int t = threadIdx.x;
    const int nbase = blockIdx.x * 64;

    const int lane = t & 63;
    const int wv = t >> 6;
    const int we0 = wv * 16;
    const int lane16 = lane & 15;
    const int lg = lane >> 4;
    const int ar = we0 + lane16;
    const int nodeA = nbase + ar;
    const int nclA = nodeA < NN ? nodeA : NN - 1;

    bf16x8 a[4];
    #pragma unroll
    for (int ks = 0; ks < 4; ++ks)
        a[ks] = *(const bf16x8*)(hbin + (size_t)nclA * D + (ks * 4 + lg) * 8);

    #pragma unroll
    for (int j = 0; j < 2; ++j)
        __builtin_amdgcn_global_load_lds(
            (const __attribute__((address_space(1))) unsigned int*)(pw1 + (j * 256 + t) * 8),
            (__attribute__((address_space(3))) unsigned int*)(sBu + (j * 256 + t) * 8), 16, 0, 0);
    __syncthreads();

    f32x4 acc[8], acc2[8];
    #pragma unroll
    for (int ct = 0; ct < 8; ++ct) acc[ct] = (f32x4){0.f, 0.f, 0.f, 0.f};

    int cur = 0;
    #pragma unroll
    for (int s = 0; s < 8; ++s) {
        if (s < 7) {
            const ushort* nsrc = (s + 1 < 4) ? (pw1 + (s + 1) * WSLICE)
                                             : (pw2 + (s + 1 - 4) * WSLICE);
            #pragma unroll
            for (int j = 0; j < 2; ++j)
                __builtin_amdgcn_global_load_lds(
                    (const __attribute__((address_space(1))) unsigned int*)(nsrc + (j * 256 + t) * 8),
                    (__attribute__((address_space(3))) unsigned int*)(sBu + (cur ^ 1) * WSLICE + (j * 256 + t) * 8), 16, 0, 0);
        }
        if (s == 4) {
            #pragma unroll
            for (int ct = 0; ct < 8; ++ct) {
                int col = ct * 16 + lane16;
                float b1v = b1[col];
                #pragma unroll
                for (int r = 0; r < 4; ++r) {
                    int er = we0 + lg * 4 + r;
                    float v = silu_f(acc[ct][r] + b1v);
                    int c2 = col >> 3;
                    sHidu[er * 128 + ((c2 ^ (er & 7)) * 8) + (col & 7)] = f2b(v);
                }
            }
            #pragma unroll
            for (int ct = 0; ct < 8; ++ct) acc2[ct] = (f32x4){0.f, 0.f, 0.f, 0.f};
        }
        if (s < 4) {
            #pragma unroll
            for (int ct = 0; ct < 8; ++ct) {
                bf16x8 b = *(const bf16x8*)(sBu + cur * WSLICE + ct * 512 + lane * 8);
                acc[ct] = __builtin_amdgcn_mfma_f32_16x16x32_bf16(a[s], b, acc[ct], 0, 0, 0);
            }
        } else {
            int c = (s - 4) * 4 + lg;
            bf16x8 ah = *(const bf16x8*)(sHidu + ar * 128 + ((c ^ (ar & 7)) * 8));
            #pragma unroll
            for (int ct = 0; ct < 8; ++ct) {
                bf16x8 b = *(const bf16x8*)(sBu + cur * WSLICE + ct * 512 + lane * 8);
                acc2[ct] = __builtin_amdgcn_mfma_f32_16x16x32_bf16(ah, b, acc2[ct], 0, 0, 0);
            }
        }
        __syncthreads();
        cur ^= 1;
    }

    // y = h + nodeMLP(h) + b2 + agg/deg
    #pragma unroll
    for (int ct = 0; ct < 8; ++ct) {
        int col = ct * 16 + lane16;
        float b2v = b2[col];
        #pragma unroll
        for (int r = 0; r < 4; ++r) {
            int er = we0 + lg * 4 + r;
            int node = nbase + er;
            int ncl = node < NN ? node : NN - 1;
            float invd = 1.0f / fmaxf((float)degi[ncl], 1.0f);
            float y = h[(size_t)ncl * D + col] + acc2[ct][r] + b2v
                    + agg[(size_t)ncl * D + col] * invd;
            acc2[ct][r] = y;
        }
    }

    #pragma unroll
    for (int r = 0; r < 4; ++r) {
        float s = 0.f, s2 = 0.f;
        #pragma unroll
        for (int ct = 0; ct < 8; ++ct) { float y = acc2[ct][r]; s += y; s2 += y * y; }
        #pragma unroll
        for (int off = 1; off < 16; off <<= 1) {
            s  += __shfl_xor(s,  off, 16);
            s2 += __shfl_xor(s2, off, 16);
        }
        float mean = s * (1.0f / D);
        float var  = s2 * (1.0f / D) - mean * mean;
        float rstd = rsqrtf(var + 1e-5f);
        int er = we0 + lg * 4 + r;
        int node = nbase + er;
        if (node < NN) {
            #pragma unroll
            for (int ct = 0; ct < 8; ++ct) {
                int col = ct * 16 + lane16;
                float v = (acc2[ct][r] - mean) * rstd * lng[col] + lnb[col];
                hout[(size_t)node * D + col] = v;
                hbout[(size_t)node * D + col] = f2b(v);
            }
        }
    }
}

extern "C" void kernel_launch(void* const* d_in, const int* in_sizes, int n_in,
                              void* d_out, int out_size, void* d_ws, size_t ws_size,
                              hipStream_t stream) {
    const float* x        = (const float*)d_in[0];
    const float* pos      = (const float*)d_in[1];
    const float* time_emb = (const float*)d_in[2];
    const float* time_w1  = (const float*)d_in[3];
    const float* time_b1  = (const float*)d_in[4];
    const float* time_w2  = (const float*)d_in[5];
    const float* time_b2  = (const float*)d_in[6];
    const float* node_w1  = (const float*)d_in[7];
    const float* node_b1  = (const float*)d_in[8];
    const float* node_w2  = (const float*)d_in[9];
    const float* node_b2  = (const float*)d_in[10];
    const float* edge_w1  = (const float*)d_in[11];
    const float* edge_b1  = (const float*)d_in[12];
    const float* edge_w2  = (const float*)d_in[13];
    const float* edge_b2  = (const float*)d_in[14];
    const float* ln_g     = (const float*)d_in[15];
    const float* ln_b     = (const float*)d_in[16];
    const int*   ei       = (const int*)d_in[17];
    const int*   batch    = (const int*)d_in[18];

    float* h = (float*)d_out;                       // [NN, D]
    float* pos_out = h + (size_t)NN * D;            // [NN, 3]

    char* w = (char*)d_ws;
    float*        tp     = (float*)w;        w += (((size_t)NBATCH * D * 4) + 255) & ~(size_t)255;
    unsigned int* degi   = (unsigned int*)w; w += (((size_t)NN * 4) + 255) & ~(size_t)255;
    unsigned int* part   = (unsigned int*)w; w += 256;
    unsigned int* starts = (unsigned int*)w; w += (((size_t)NN * 4) + 255) & ~(size_t)255;
    int*          srow   = (int*)w;          w += (((size_t)NE * 4) + 255) & ~(size_t)255;
    int*          scol   = (int*)w;          w += (((size_t)NE * 4) + 255) & ~(size_t)255;
    float*        sdist  = (float*)w;        w += (((size_t)NE * 4) + 255) & ~(size_t)255;
    float*        agg    = (float*)w;        w += (((size_t)NN * D * 4) + 255) & ~(size_t)255;
    ushort*       hb     = (ushort*)w;       w += (((size_t)NN * D * 2) + 255) & ~(size_t)255;
    ushort*       pwE1   = (ushort*)w;       w += (((size_t)NLAYERS * 32768 * 2) + 255) & ~(size_t)255;
    ushort*       pwE2   = (ushort*)w;       w += (((size_t)NLAYERS * 16384 * 2) + 255) & ~(size_t)255;
    ushort*       pwN1   = (ushort*)w;       w += (((size_t)NLAYERS * 16384 * 2) + 255) & ~(size_t)255;
    ushort*       pwN2   = (ushort*)w;       w += (((size_t)NLAYERS * 16384 * 2) + 255) & ~(size_t)255;

    hipMemsetAsync(degi, 0, (size_t)NN * 4, stream);
    k_time_mlp<<<NBATCH, D, 0, stream>>>(time_emb, time_w1, time_b1, time_w2, time_b2, tp);
    k_init_h<<<(NN * D) / 256, 256, 0, stream>>>(x, tp, batch, h, hb);
    k_deg<<<NE / 256, 256, 0, stream>>>(ei + NE, degi);

    k_scan_a<<<SCANB, 256, 0, stream>>>(degi, part);
    k_scan_b<<<1, 64, 0, stream>>>(part);
    k_scan_c<<<SCANB, 256, 0, stream>>>(degi, part, starts);
    k_sort<<<NE / 256, 256, 0, stream>>>(ei, starts, srow, scol);
    k_dist<<<NE / 256, 256, 0, stream>>>(srow, scol, pos, sdist);

    // weight pre-pack (slice-major fragment layout)
    k_pack<<<(NLAYERS * 32768) / 256, 256, 0, stream>>>(edge_w1, pwE1, 257 * 128, 32768);
    k_pack<<<(NLAYERS * 16384) / 256, 256, 0, stream>>>(edge_w2, pwE2, 128 * 128, 16384);
    k_pack<<<(NLAYERS * 16384) / 256, 256, 0, stream>>>(node_w1, pwN1, 128 * 128, 16384);
    k_pack<<<(NLAYERS * 16384) / 256, 256, 0, stream>>>(node_w2, pwN2, 128 * 128, 16384);

    for (int l = 0; l < NLAYERS; ++l) {
        hipMemsetAsync(agg, 0, (size_t)NN * D * 4, stream);
        k_edge<<<256, 512, 0, stream>>>(hb, srow, scol, sdist,
            pwE1 + (size_t)l * 32768, pwE2 + (size_t)l * 16384,
            edge_w1 + (size_t)l * (2 * D + 1) * D, edge_b1 + (size_t)l * D,
            edge_b2 + (size_t)l * D, agg);
        k_node<<<(NN + 63) / 64, 256, 0, stream>>>(h, hb, agg, degi,
            pwN1 + (size_t)l * 16384, pwN2 + (size_t)l * 16384,
            node_b1 + (size_t)l * D, node_b2 + (size_t)l * D,
            ln_g + (size_t)l * D, ln_b + (size_t)l * D, h, hb);
    }
    hipMemcpyAsync(pos_out, pos, (size_t)NN * 3 * 4, hipMemcpyDeviceToDevice, stream);
}

// Round 6
// 1188.120 us; speedup vs baseline: 1.6440x; 1.0514x over previous
//
#include <hip/hip_runtime.h>
#include <hip/hip_bf16.h>
#include <math.h>

#define NN 50000
#define NE 800000
#define D 128
#define NBATCH 32
#define NLAYERS 3
#define SCANB ((NN + 1023) / 1024)   // 49
#define WSLICE 4096                  // ushorts per 8KB weight K-slice
#define ESUB 40                      // edges per 16-lane group
#define EBLK (NE / (16 * ESUB))      // 1250 blocks

typedef __attribute__((ext_vector_type(8))) short bf16x8;
typedef __attribute__((ext_vector_type(4))) float f32x4;

__device__ __forceinline__ float silu_f(float x) {
    return x / (1.0f + __expf(-x));
}
__device__ __forceinline__ ushort f2b(float v) {
    __hip_bfloat16 b = __float2bfloat16(v);
    return *(ushort*)&b;
}
__device__ __forceinline__ float b2f(ushort u) {
    return __uint_as_float(((unsigned)u) << 16);
}

// ---------------- time MLP ----------------
__global__ void k_time_mlp(const float* __restrict__ te,
                           const float* __restrict__ w1, const float* __restrict__ b1,
                           const float* __restrict__ w2, const float* __restrict__ b2,
                           float* __restrict__ tp) {
    __shared__ float s_in[D];
    __shared__ float s_hid[D];
    const int b = blockIdx.x;
    const int j = threadIdx.x;
    s_in[j] = te[b * D + j];
    __syncthreads();
    float acc = b1[j];
    for (int k = 0; k < D; ++k) acc = fmaf(s_in[k], w1[k * D + j], acc);
    s_hid[j] = silu_f(acc);
    __syncthreads();
    float acc2 = b2[j];
    for (int k = 0; k < D; ++k) acc2 = fmaf(s_hid[k], w2[k * D + j], acc2);
    tp[b * D + j] = acc2;
}

// ---------------- h = x + tp[batch]; also h_bf16 ----------------
__global__ void k_init_h(const float* __restrict__ x, const float* __restrict__ tp,
                         const int* __restrict__ batch, float* __restrict__ h,
                         ushort* __restrict__ hb) {
    int idx = blockIdx.x * 256 + threadIdx.x;
    int n = idx >> 7, c = idx & 127;
    float v = x[idx] + tp[batch[n] * D + c];
    h[idx] = v;
    hb[idx] = f2b(v);
}

// ---------------- integer degree ----------------
__global__ void k_deg(const int* __restrict__ col, unsigned int* __restrict__ deg) {
    int e = blockIdx.x * 256 + threadIdx.x;
    atomicAdd(&deg[col[e]], 1u);
}

// ---------------- exclusive scan over deg ----------------
__global__ void k_scan_a(const unsigned int* __restrict__ deg, unsigned int* __restrict__ part) {
    __shared__ unsigned int sl[256];
    int b = blockIdx.x, t = threadIdx.x;
    unsigned int s = 0;
    #pragma unroll
    for (int i = 0; i < 4; ++i) {
        int idx = b * 1024 + t * 4 + i;
        if (idx < NN) s += deg[idx];
    }
    sl[t] = s; __syncthreads();
    for (int off = 128; off; off >>= 1) {
        if (t < off) sl[t] += sl[t + off];
        __syncthreads();
    }
    if (t == 0) part[b] = sl[0];
}
__global__ void k_scan_b(unsigned int* __restrict__ part) {
    __shared__ unsigned int sp[64];
    int t = threadIdx.x;
    sp[t] = (t < SCANB) ? part[t] : 0u;
    __syncthreads();
    if (t == 0) {
        unsigned int run = 0;
        for (int i = 0; i < SCANB; ++i) { unsigned int v = sp[i]; sp[i] = run; run += v; }
    }
    __syncthreads();
    if (t < SCANB) part[t] = sp[t];
}
__global__ void k_scan_c(const unsigned int* __restrict__ deg, const unsigned int* __restrict__ part,
                         unsigned int* __restrict__ starts) {
    __shared__ unsigned int sl[256];
    int b = blockIdx.x, t = threadIdx.x;
    unsigned int v4[4]; unsigned int s = 0;
    #pragma unroll
    for (int i = 0; i < 4; ++i) {
        int idx = b * 1024 + t * 4 + i;
        v4[i] = (idx < NN) ? deg[idx] : 0u;
        s += v4[i];
    }
    sl[t] = s; __syncthreads();
    if (t == 0) {
        unsigned int run = 0;
        for (int i = 0; i < 256; ++i) { unsigned int x = sl[i]; sl[i] = run; run += x; }
    }
    __syncthreads();
    unsigned int off = part[b] + sl[t];
    #pragma unroll
    for (int i = 0; i < 4; ++i) {
        int idx = b * 1024 + t * 4 + i;
        if (idx < NN) { starts[idx] = off; off += v4[i]; }
    }
}

// ---------------- counting-sort placement ----------------
__global__ void k_sort(const int* __restrict__ ei, unsigned int* __restrict__ cursor,
                       int* __restrict__ srow, int* __restrict__ scol) {
    int e = blockIdx.x * 256 + threadIdx.x;
    int r = ei[e], c = ei[NE + e];
    unsigned int p = atomicAdd(&cursor[c], 1u);
    srow[p] = r; scol[p] = c;
}

// ---------------- per-edge distance (sorted order) ----------------
__global__ void k_dist(const int* __restrict__ srow, const int* __restrict__ scol,
                       const float* __restrict__ pos, float* __restrict__ sdist) {
    int e = blockIdx.x * 256 + threadIdx.x;
    int r = srow[e], c = scol[e];
    float dx = pos[r * 3 + 0] - pos[c * 3 + 0];
    float dy = pos[r * 3 + 1] - pos[c * 3 + 1];
    float dz = pos[r * 3 + 2] - pos[c * 3 + 2];
    sdist[e] = sqrtf(dx * dx + dy * dy + dz * dz);
}

// ---------------- weight pre-pack: slice-major bf16 [ks][ct][lane][8] ----------------
__global__ void k_pack(const float* __restrict__ W, ushort* __restrict__ out,
                       int layerStrideW, int totalPerLayer) {
    int t = blockIdx.x * 256 + threadIdx.x;
    int l = t / totalPerLayer;
    int r = t - l * totalPerLayer;
    int j = r & 7;
    int lane = (r >> 3) & 63;
    int ct = (r >> 9) & 7;
    int ks = r >> 12;
    int k = ks * 32 + ((lane >> 4) << 3) + j;
    int n = ct * 16 + (lane & 15);
    out[t] = f2b(W[(size_t)l * layerStrideW + k * 128 + n]);
}

__device__ __forceinline__ void stage8k(const ushort* __restrict__ src, ushort* dst, int t) {
    __builtin_amdgcn_global_load_lds(
        (const __attribute__((address_space(1))) unsigned int*)(src + t * 8),
        (__attribute__((address_space(3))) unsigned int*)(dst + t * 8), 16, 0, 0);
    __builtin_amdgcn_global_load_lds(
        (const __attribute__((address_space(1))) unsigned int*)(src + 2048 + t * 8),
        (__attribute__((address_space(3))) unsigned int*)(dst + 2048 + t * 8), 16, 0, 0);
}

// ---------------- C1 = h@W1a + b1, R1 = h@W1b (node-space, bf16 out) ----------------
__global__ __launch_bounds__(256, 4)
void k_c1r1(const ushort* __restrict__ hbin,
            const ushort* __restrict__ pwA, const ushort* __restrict__ pwB,
            const float* __restrict__ b1,
            ushort* __restrict__ C1, ushort* __restrict__ R1) {
    __shared__ ushort sBu[2 * WSLICE];

    const int t = threadIdx.x;
    const int nbase = blockIdx.x * 64;
    const int lane = t & 63;
    const int wv = t >> 6;
    const int we0 = wv * 16;
    const int lane16 = lane & 15;
    const int lg = lane >> 4;
    const int ar = we0 + lane16;
    const int nodeA = nbase + ar;
    const int nclA = nodeA < NN ? nodeA : NN - 1;

    bf16x8 a[4];
    #pragma unroll
    for (int ks = 0; ks < 4; ++ks)
        a[ks] = *(const bf16x8*)(hbin + (size_t)nclA * D + (ks * 4 + lg) * 8);

    stage8k(pwA, sBu, t);
    __syncthreads();

    f32x4 acc1[8], acc2[8];
    #pragma unroll
    for (int ct = 0; ct < 8; ++ct) {
        acc1[ct] = (f32x4){0.f, 0.f, 0.f, 0.f};
        acc2[ct] = (f32x4){0.f, 0.f, 0.f, 0.f};
    }

    int cur = 0;
    #pragma unroll
    for (int s = 0; s < 8; ++s) {
        if (s < 7) {
            const ushort* nsrc = (s + 1 < 4) ? (pwA + (s + 1) * WSLICE)
                                             : (pwB + (s + 1 - 4) * WSLICE);
            stage8k(nsrc, sBu + (cur ^ 1) * WSLICE, t);
        }
        int ks = s & 3;
        if (s < 4) {
            #pragma unroll
            for (int ct = 0; ct < 8; ++ct) {
                bf16x8 b = *(const bf16x8*)(sBu + cur * WSLICE + ct * 512 + lane * 8);
                acc1[ct] = __builtin_amdgcn_mfma_f32_16x16x32_bf16(a[ks], b, acc1[ct], 0, 0, 0);
            }
        } else {
            #pragma unroll
            for (int ct = 0; ct < 8; ++ct) {
                bf16x8 b = *(const bf16x8*)(sBu + cur * WSLICE + ct * 512 + lane * 8);
                acc2[ct] = __builtin_amdgcn_mfma_f32_16x16x32_bf16(a[ks], b, acc2[ct], 0, 0, 0);
            }
        }
        __syncthreads();
        cur ^= 1;
    }

    #pragma unroll
    for (int ct = 0; ct < 8; ++ct) {
        int col = ct * 16 + lane16;
        float b1v = b1[col];
        #pragma unroll
        for (int r = 0; r < 4; ++r) {
            int node = nbase + we0 + lg * 4 + r;
            if (node < NN) {
                C1[(size_t)node * D + col] = f2b(acc1[ct][r] + b1v);
                R1[(size_t)node * D + col] = f2b(acc2[ct][r]);
            }
        }
    }
}

// ---------------- edge streaming: hid = silu(C1[col]+R1[row]+d*wd), run-merged scatter ----------------
// 256 threads = 16 groups of 16 lanes; each group owns ESUB consecutive sorted edges.
__global__ __launch_bounds__(256)
void k_edge2(const ushort* __restrict__ C1, const ushort* __restrict__ R1,
             const int* __restrict__ srow, const int* __restrict__ scol,
             const float* __restrict__ sdist, const float* __restrict__ w1f,
             float* __restrict__ Hagg) {
    const int t = threadIdx.x;
    const int g = blockIdx.x * 16 + (t >> 4);
    const int l = t & 15;
    const int e0 = g * ESUB;

    float wd[8];
    #pragma unroll
    for (int i = 0; i < 8; ++i) wd[i] = w1f[256 * D + l * 8 + i];

    // 2-deep software pipeline: idx(i+2), rows(i+1), compute(i)
    int col0 = scol[e0],     row0 = srow[e0];     float d0 = sdist[e0];
    int col1 = scol[e0 + 1], row1 = srow[e0 + 1]; float d1 = sdist[e0 + 1];
    bf16x8 c1v = *(const bf16x8*)(C1 + (size_t)col0 * D + l * 8);
    bf16x8 r1v = *(const bf16x8*)(R1 + (size_t)row0 * D + l * 8);

    float acc[8];
    #pragma unroll
    for (int i = 0; i < 8; ++i) acc[i] = 0.f;
    int prev = col0;

    for (int i = 0; i < ESUB; ++i) {
        int e = e0 + i;
        int col2 = col1, row2 = row1; float d2 = d1;
        if (i + 2 < ESUB) { col2 = scol[e + 2]; row2 = srow[e + 2]; d2 = sdist[e + 2]; }
        bf16x8 c1n = c1v, r1n = r1v;
        if (i + 1 < ESUB) {
            c1n = *(const bf16x8*)(C1 + (size_t)col1 * D + l * 8);
            r1n = *(const bf16x8*)(R1 + (size_t)row1 * D + l * 8);
        }

        if (col0 != prev) {
            float* dst = Hagg + (size_t)prev * D + l * 8;
            #pragma unroll
            for (int k = 0; k < 8; ++k) { unsafeAtomicAdd(dst + k, acc[k]); acc[k] = 0.f; }
            prev = col0;
        }
        #pragma unroll
        for (int k = 0; k < 8; ++k) {
            float x = b2f(c1v[k]) + b2f(r1v[k]) + d0 * wd[k];
            acc[k] += x / (1.0f + __expf(-x));
        }

        col0 = col1; row0 = row1; d0 = d1;
        col1 = col2; row1 = row2; d1 = d2;
        c1v = c1n; r1v = r1n;
    }
    float* dst = Hagg + (size_t)prev * D + l * 8;
    #pragma unroll
    for (int k = 0; k < 8; ++k) unsafeAtomicAdd(dst + k, acc[k]);
}

// ---------------- fused node update: nodeMLP + Hagg@W2/deg + b2 + residual + LN ----------------
__global__ __launch_bounds__(256, 4)
void k_node(const float* __restrict__ h, const ushort* __restrict__ hbin,
            const float* __restrict__ Hagg, const unsigned int* __restrict__ degi,
            const ushort* __restrict__ pw1, const ushort* __restrict__ pwE2v,
            const ushort* __restrict__ pw2,
            const float* __restrict__ b1, const float* __restrict__ b2n,
            const float* __restrict__ b2e,
            const float* __restrict__ lng, const float* __restrict__ lnb,
            float* __restrict__ hout, ushort* __restrict__ hbout) {
    __shared__ ushort sBu[2 * WSLICE];    // 16 KB
    __shared__ ushort sHidu[64 * 128];    // 16 KB

    const int t = threadIdx.x;
    const int nbase = blockIdx.x * 64;
    const int lane = t & 63;
    const int wv = t >> 6;
    const int we0 = wv * 16;
    const int lane16 = lane & 15;
    const int lg = lane >> 4;
    const int ar = we0 + lane16;
    const int nodeA = nbase + ar;
    const int nclA = nodeA < NN ? nodeA : NN - 1;

    bf16x8 a_h[4], a_g[4];
    #pragma unroll
    for (int ks = 0; ks < 4; ++ks)
        a_h[ks] = *(const bf16x8*)(hbin + (size_t)nclA * D + (ks * 4 + lg) * 8);
    #pragma unroll
    for (int ks = 0; ks < 4; ++ks) {
        f32x4 u0 = *(const f32x4*)(Hagg + (size_t)nclA * D + (ks * 4 + lg) * 8);
        f32x4 u1 = *(const f32x4*)(Hagg + (size_t)nclA * D + (ks * 4 + lg) * 8 + 4);
        bf16x8 v;
        #pragma unroll
        for (int j = 0; j < 4; ++j) { v[j] = (short)f2b(u0[j]); v[4 + j] = (short)f2b(u1[j]); }
        a_g[ks] = v;
    }

    stage8k(pw1, sBu, t);
    __syncthreads();

    f32x4 acc1[8], acc2[8], acc3[8];
    #pragma unroll
    for (int ct = 0; ct < 8; ++ct) {
        acc1[ct] = (f32x4){0.f, 0.f, 0.f, 0.f};
        acc2[ct] = (f32x4){0.f, 0.f, 0.f, 0.f};
        acc3[ct] = (f32x4){0.f, 0.f, 0.f, 0.f};
    }

    int cur = 0;
    #pragma unroll
    for (int s = 0; s < 12; ++s) {
        if (s < 11) {
            const ushort* nsrc = (s + 1 < 4) ? (pw1 + (s + 1) * WSLICE)
                               : (s + 1 < 8) ? (pwE2v + (s + 1 - 4) * WSLICE)
                                             : (pw2 + (s + 1 - 8) * WSLICE);
            stage8k(nsrc, sBu + (cur ^ 1) * WSLICE, t);
        }
        if (s == 4) {
            // epilogue 1: silu(acc1 + b1) -> sHidu (wave-local rows, swizzled)
            #pragma unroll
            for (int ct = 0; ct < 8; ++ct) {
                int col = ct * 16 + lane16;
                float b1v = b1[col];
                #pragma unroll
                for (int r = 0; r < 4; ++r) {
                    int er = we0 + lg * 4 + r;
                    float v = silu_f(acc1[ct][r] + b1v);
                    int c2 = col >> 3;
                    sHidu[er * 128 + ((c2 ^ (er & 7)) * 8) + (col & 7)] = f2b(v);
                }
            }
        }
        if (s < 4) {
            #pragma unroll
            for (int ct = 0; ct < 8; ++ct) {
                bf16x8 b = *(const bf16x8*)(sBu + cur * WSLICE + ct * 512 + lane * 8);
                acc1[ct] = __builtin_amdgcn_mfma_f32_16x16x32_bf16(a_h[s], b, acc1[ct], 0, 0, 0);
            }
        } else if (s < 8) {
            #pragma unroll
            for (int ct = 0; ct < 8; ++ct) {
                bf16x8 b = *(const bf16x8*)(sBu + cur * WSLICE + ct * 512 + lane * 8);
                acc3[ct] = __builtin_amdgcn_mfma_f32_16x16x32_bf16(a_g[s - 4], b, acc3[ct], 0, 0, 0);
            }
        } else {
            int c = (s - 8) * 4 + lg;
            bf16x8 ah = *(const bf16x8*)(sHidu + ar * 128 + ((c ^ (ar & 7)) * 8));
            #pragma unroll
            for (int ct = 0; ct < 8; ++ct) {
                bf16x8 b = *(const bf16x8*)(sBu + cur * WSLICE + ct * 512 + lane * 8);
                acc2[ct] = __builtin_amdgcn_mfma_f32_16x16x32_bf16(ah, b, acc2[ct], 0, 0, 0);
            }
        }
        __syncthreads();
        cur ^= 1;
    }

    // y = h + nodeMLP(h) + b2n + Hagg@W2 * invd + [deg>0] b2e
    #pragma unroll
    for (int ct = 0; ct < 8; ++ct) {
        int col = ct * 16 + lane16;
        float b2nv = b2n[col];
        float b2ev = b2e[col];
        #pragma unroll
        for (int r = 0; r < 4; ++r) {
            int er = we0 + lg * 4 + r;
            int node = nbase + er;
            int ncl = node < NN ? node : NN - 1;
            unsigned int dg = degi[ncl];
            float invd = 1.0f / fmaxf((float)dg, 1.0f);
            float y = h[(size_t)ncl * D + col] + acc2[ct][r] + b2nv
                    + acc3[ct][r] * invd + (dg > 0 ? b2ev : 0.0f);
            acc2[ct][r] = y;
        }
    }

    #pragma unroll
    for (int r = 0; r < 4; ++r) {
        float s = 0.f, s2 = 0.f;
        #pragma unroll
        for (int ct = 0; ct < 8; ++ct) { float y = acc2[ct][r]; s += y; s2 += y * y; }
        #pragma unroll
        for (int off = 1; off < 16; off <<= 1) {
            s  += __shfl_xor(s,  off, 16);
            s2 += __shfl_xor(s2, off, 16);
        }
        float mean = s * (1.0f / D);
        float var  = s2 * (1.0f / D) - mean * mean;
        float rstd = rsqrtf(var + 1e-5f);
        int node = nbase + we0 + lg * 4 + r;
        if (node < NN) {
            #pragma unroll
            for (int ct = 0; ct < 8; ++ct) {
                int col = ct * 16 + lane16;
                float v = (acc2[ct][r] - mean) * rstd * lng[col] + lnb[col];
                hout[(size_t)node * D + col] = v;
                hbout[(size_t)node * D + col] = f2b(v);
            }
        }
    }
}

extern "C" void kernel_launch(void* const* d_in, const int* in_sizes, int n_in,
                              void* d_out, int out_size, void* d_ws, size_t ws_size,
                              hipStream_t stream) {
    const float* x        = (const float*)d_in[0];
    const float* pos      = (const float*)d_in[1];
    const float* time_emb = (const float*)d_in[2];
    const float* time_w1  = (const float*)d_in[3];
    const float* time_b1  = (const float*)d_in[4];
    const float* time_w2  = (const float*)d_in[5];
    const float* time_b2  = (const float*)d_in[6];
    const float* node_w1  = (const float*)d_in[7];
    const float* node_b1  = (const float*)d_in[8];
    const float* node_w2  = (const float*)d_in[9];
    const float* node_b2  = (const float*)d_in[10];
    const float* edge_w1  = (const float*)d_in[11];
    const float* edge_b1  = (const float*)d_in[12];
    const float* edge_w2  = (const float*)d_in[13];
    const float* edge_b2  = (const float*)d_in[14];
    const float* ln_g     = (const float*)d_in[15];
    const float* ln_b     = (const float*)d_in[16];
    const int*   ei       = (const int*)d_in[17];
    const int*   batch    = (const int*)d_in[18];

    float* h = (float*)d_out;                       // [NN, D]
    float* pos_out = h + (size_t)NN * D;            // [NN, 3]

    char* w = (char*)d_ws;
    float*        tp     = (float*)w;        w += (((size_t)NBATCH * D * 4) + 255) & ~(size_t)255;
    unsigned int* degi   = (unsigned int*)w; w += (((size_t)NN * 4) + 255) & ~(size_t)255;
    unsigned int* part   = (unsigned int*)w; w += 256;
    unsigned int* starts = (unsigned int*)w; w += (((size_t)NN * 4) + 255) & ~(size_t)255;
    int*          srow   = (int*)w;          w += (((size_t)NE * 4) + 255) & ~(size_t)255;
    int*          scol   = (int*)w;          w += (((size_t)NE * 4) + 255) & ~(size_t)255;
    float*        sdist  = (float*)w;        w += (((size_t)NE * 4) + 255) & ~(size_t)255;
    float*        Hagg   = (float*)w;        w += (((size_t)NN * D * 4) + 255) & ~(size_t)255;
    ushort*       hb     = (ushort*)w;       w += (((size_t)NN * D * 2) + 255) & ~(size_t)255;
    ushort*       C1     = (ushort*)w;       w += (((size_t)NN * D * 2) + 255) & ~(size_t)255;
    ushort*       R1     = (ushort*)w;       w += (((size_t)NN * D * 2) + 255) & ~(size_t)255;
    ushort*       pwA    = (ushort*)w;       w += (((size_t)NLAYERS * 16384 * 2) + 255) & ~(size_t)255;
    ushort*       pwB    = (ushort*)w;       w += (((size_t)NLAYERS * 16384 * 2) + 255) & ~(size_t)255;
    ushort*       pwE2   = (ushort*)w;       w += (((size_t)NLAYERS * 16384 * 2) + 255) & ~(size_t)255;
    ushort*       pwN1   = (ushort*)w;       w += (((size_t)NLAYERS * 16384 * 2) + 255) & ~(size_t)255;
    ushort*       pwN2   = (ushort*)w;       w += (((size_t)NLAYERS * 16384 * 2) + 255) & ~(size_t)255;

    hipMemsetAsync(degi, 0, (size_t)NN * 4, stream);
    k_time_mlp<<<NBATCH, D, 0, stream>>>(time_emb, time_w1, time_b1, time_w2, time_b2, tp);
    k_init_h<<<(NN * D) / 256, 256, 0, stream>>>(x, tp, batch, h, hb);
    k_deg<<<NE / 256, 256, 0, stream>>>(ei + NE, degi);

    k_scan_a<<<SCANB, 256, 0, stream>>>(degi, part);
    k_scan_b<<<1, 64, 0, stream>>>(part);
    k_scan_c<<<SCANB, 256, 0, stream>>>(degi, part, starts);
    k_sort<<<NE / 256, 256, 0, stream>>>(ei, starts, srow, scol);
    k_dist<<<NE / 256, 256, 0, stream>>>(srow, scol, pos, sdist);

    // weight pre-pack (slice-major fragment layout, all 128x128)
    k_pack<<<(NLAYERS * 16384) / 256, 256, 0, stream>>>(edge_w1, pwA, 257 * 128, 16384);
    k_pack<<<(NLAYERS * 16384) / 256, 256, 0, stream>>>(edge_w1 + 128 * 128, pwB, 257 * 128, 16384);
    k_pack<<<(NLAYERS * 16384) / 256, 256, 0, stream>>>(edge_w2, pwE2, 128 * 128, 16384);
    k_pack<<<(NLAYERS * 16384) / 256, 256, 0, stream>>>(node_w1, pwN1, 128 * 128, 16384);
    k_pack<<<(NLAYERS * 16384) / 256, 256, 0, stream>>>(node_w2, pwN2, 128 * 128, 16384);

    const int NBLK = (NN + 63) / 64;
    for (int l = 0; l < NLAYERS; ++l) {
        hipMemsetAsync(Hagg, 0, (size_t)NN * D * 4, stream);
        k_c1r1<<<NBLK, 256, 0, stream>>>(hb,
            pwA + (size_t)l * 16384, pwB + (size_t)l * 16384,
            edge_b1 + (size_t)l * D, C1, R1);
        k_edge2<<<EBLK, 256, 0, stream>>>(C1, R1, srow, scol, sdist,
            edge_w1 + (size_t)l * (2 * D + 1) * D, Hagg);
        k_node<<<NBLK, 256, 0, stream>>>(h, hb, Hagg, degi,
            pwN1 + (size_t)l * 16384, pwE2 + (size_t)l * 16384, pwN2 + (size_t)l * 16384,
            node_b1 + (size_t)l * D, node_b2 + (size_t)l * D, edge_b2 + (size_t)l * D,
            ln_g + (size_t)l * D, ln_b + (size_t)l * D, h, hb);
    }
    hipMemcpyAsync(pos_out, pos, (size_t)NN * 3 * 4, hipMemcpyDeviceToDevice, stream);
}

// Round 7
// 597.143 us; speedup vs baseline: 3.2710x; 1.9897x over previous
//
#include <hip/hip_runtime.h>
#include <hip/hip_bf16.h>
#include <math.h>

#define NN 50000
#define NE 800000
#define D 128
#define NBATCH 32
#define NLAYERS 3
#define SCANB ((NN + 1023) / 1024)   // 49
#define WSLICE 4096                  // ushorts per 8KB weight K-slice

typedef __attribute__((ext_vector_type(8))) short bf16x8;
typedef __attribute__((ext_vector_type(4))) float f32x4;

__device__ __forceinline__ float silu_f(float x) {
    return x / (1.0f + __expf(-x));
}
__device__ __forceinline__ ushort f2b(float v) {
    __hip_bfloat16 b = __float2bfloat16(v);
    return *(ushort*)&b;
}
__device__ __forceinline__ float b2f(ushort u) {
    return __uint_as_float(((unsigned)u) << 16);
}

// ---------------- time MLP ----------------
__global__ void k_time_mlp(const float* __restrict__ te,
                           const float* __restrict__ w1, const float* __restrict__ b1,
                           const float* __restrict__ w2, const float* __restrict__ b2,
                           float* __restrict__ tp) {
    __shared__ float s_in[D];
    __shared__ float s_hid[D];
    const int b = blockIdx.x;
    const int j = threadIdx.x;
    s_in[j] = te[b * D + j];
    __syncthreads();
    float acc = b1[j];
    for (int k = 0; k < D; ++k) acc = fmaf(s_in[k], w1[k * D + j], acc);
    s_hid[j] = silu_f(acc);
    __syncthreads();
    float acc2 = b2[j];
    for (int k = 0; k < D; ++k) acc2 = fmaf(s_hid[k], w2[k * D + j], acc2);
    tp[b * D + j] = acc2;
}

// ---------------- h = x + tp[batch]; also h_bf16 ----------------
__global__ void k_init_h(const float* __restrict__ x, const float* __restrict__ tp,
                         const int* __restrict__ batch, float* __restrict__ h,
                         ushort* __restrict__ hb) {
    int idx = blockIdx.x * 256 + threadIdx.x;
    int n = idx >> 7, c = idx & 127;
    float v = x[idx] + tp[batch[n] * D + c];
    h[idx] = v;
    hb[idx] = f2b(v);
}

// ---------------- integer degree ----------------
__global__ void k_deg(const int* __restrict__ col, unsigned int* __restrict__ deg) {
    int e = blockIdx.x * 256 + threadIdx.x;
    atomicAdd(&deg[col[e]], 1u);
}

// ---------------- exclusive scan over deg ----------------
__global__ void k_scan_a(const unsigned int* __restrict__ deg, unsigned int* __restrict__ part) {
    __shared__ unsigned int sl[256];
    int b = blockIdx.x, t = threadIdx.x;
    unsigned int s = 0;
    #pragma unroll
    for (int i = 0; i < 4; ++i) {
        int idx = b * 1024 + t * 4 + i;
        if (idx < NN) s += deg[idx];
    }
    sl[t] = s; __syncthreads();
    for (int off = 128; off; off >>= 1) {
        if (t < off) sl[t] += sl[t + off];
        __syncthreads();
    }
    if (t == 0) part[b] = sl[0];
}
__global__ void k_scan_b(unsigned int* __restrict__ part) {
    __shared__ unsigned int sp[64];
    int t = threadIdx.x;
    sp[t] = (t < SCANB) ? part[t] : 0u;
    __syncthreads();
    if (t == 0) {
        unsigned int run = 0;
        for (int i = 0; i < SCANB; ++i) { unsigned int v = sp[i]; sp[i] = run; run += v; }
    }
    __syncthreads();
    if (t < SCANB) part[t] = sp[t];
}
__global__ void k_scan_c(const unsigned int* __restrict__ deg, const unsigned int* __restrict__ part,
                         unsigned int* __restrict__ starts, unsigned int* __restrict__ cursor) {
    __shared__ unsigned int sl[256];
    int b = blockIdx.x, t = threadIdx.x;
    unsigned int v4[4]; unsigned int s = 0;
    #pragma unroll
    for (int i = 0; i < 4; ++i) {
        int idx = b * 1024 + t * 4 + i;
        v4[i] = (idx < NN) ? deg[idx] : 0u;
        s += v4[i];
    }
    sl[t] = s; __syncthreads();
    if (t == 0) {
        unsigned int run = 0;
        for (int i = 0; i < 256; ++i) { unsigned int x = sl[i]; sl[i] = run; run += x; }
    }
    __syncthreads();
    unsigned int off = part[b] + sl[t];
    #pragma unroll
    for (int i = 0; i < 4; ++i) {
        int idx = b * 1024 + t * 4 + i;
        if (idx < NN) { starts[idx] = off; cursor[idx] = off; off += v4[i]; }
    }
}

// ---------------- counting-sort placement ----------------
__global__ void k_sort(const int* __restrict__ ei, unsigned int* __restrict__ cursor,
                       int* __restrict__ srow, int* __restrict__ scol) {
    int e = blockIdx.x * 256 + threadIdx.x;
    int r = ei[e], c = ei[NE + e];
    unsigned int p = atomicAdd(&cursor[c], 1u);
    srow[p] = r; scol[p] = c;
}

// ---------------- per-edge distance (sorted order) ----------------
__global__ void k_dist(const int* __restrict__ srow, const int* __restrict__ scol,
                       const float* __restrict__ pos, float* __restrict__ sdist) {
    int e = blockIdx.x * 256 + threadIdx.x;
    int r = srow[e], c = scol[e];
    float dx = pos[r * 3 + 0] - pos[c * 3 + 0];
    float dy = pos[r * 3 + 1] - pos[c * 3 + 1];
    float dz = pos[r * 3 + 2] - pos[c * 3 + 2];
    sdist[e] = sqrtf(dx * dx + dy * dy + dz * dz);
}

// ---------------- weight pre-pack: slice-major bf16 [ks][ct][lane][8] ----------------
__global__ void k_pack(const float* __restrict__ W, ushort* __restrict__ out,
                       int layerStrideW, int totalPerLayer) {
    int t = blockIdx.x * 256 + threadIdx.x;
    int l = t / totalPerLayer;
    int r = t - l * totalPerLayer;
    int j = r & 7;
    int lane = (r >> 3) & 63;
    int ct = (r >> 9) & 7;
    int ks = r >> 12;
    int k = ks * 32 + ((lane >> 4) << 3) + j;
    int n = ct * 16 + (lane & 15);
    out[t] = f2b(W[(size_t)l * layerStrideW + k * 128 + n]);
}

__device__ __forceinline__ void stage8k(const ushort* __restrict__ src, ushort* dst, int t) {
    __builtin_amdgcn_global_load_lds(
        (const __attribute__((address_space(1))) unsigned int*)(src + t * 8),
        (__attribute__((address_space(3))) unsigned int*)(dst + t * 8), 16, 0, 0);
    __builtin_amdgcn_global_load_lds(
        (const __attribute__((address_space(1))) unsigned int*)(src + 2048 + t * 8),
        (__attribute__((address_space(3))) unsigned int*)(dst + 2048 + t * 8), 16, 0, 0);
}

// ---------------- C1 = h@W1a + b1, R1 = h@W1b (node-space, bf16 out) ----------------
__global__ __launch_bounds__(256, 4)
void k_c1r1(const ushort* __restrict__ hbin,
            const ushort* __restrict__ pwA, const ushort* __restrict__ pwB,
            const float* __restrict__ b1,
            ushort* __restrict__ C1, ushort* __restrict__ R1) {
    __shared__ ushort sBu[2 * WSLICE];

    const int t = threadIdx.x;
    const int nbase = blockIdx.x * 64;
    const int lane = t & 63;
    const int wv = t >> 6;
    const int we0 = wv * 16;
    const int lane16 = lane & 15;
    const int lg = lane >> 4;
    const int ar = we0 + lane16;
    const int nodeA = nbase + ar;
    const int nclA = nodeA < NN ? nodeA : NN - 1;

    bf16x8 a[4];
    #pragma unroll
    for (int ks = 0; ks < 4; ++ks)
        a[ks] = *(const bf16x8*)(hbin + (size_t)nclA * D + (ks * 4 + lg) * 8);

    stage8k(pwA, sBu, t);
    __syncthreads();

    f32x4 acc1[8], acc2[8];
    #pragma unroll
    for (int ct = 0; ct < 8; ++ct) {
        acc1[ct] = (f32x4){0.f, 0.f, 0.f, 0.f};
        acc2[ct] = (f32x4){0.f, 0.f, 0.f, 0.f};
    }

    int cur = 0;
    #pragma unroll
    for (int s = 0; s < 8; ++s) {
        if (s < 7) {
            const ushort* nsrc = (s + 1 < 4) ? (pwA + (s + 1) * WSLICE)
                                             : (pwB + (s + 1 - 4) * WSLICE);
            stage8k(nsrc, sBu + (cur ^ 1) * WSLICE, t);
        }
        int ks = s & 3;
        if (s < 4) {
            #pragma unroll
            for (int ct = 0; ct < 8; ++ct) {
                bf16x8 b = *(const bf16x8*)(sBu + cur * WSLICE + ct * 512 + lane * 8);
                acc1[ct] = __builtin_amdgcn_mfma_f32_16x16x32_bf16(a[ks], b, acc1[ct], 0, 0, 0);
            }
        } else {
            #pragma unroll
            for (int ct = 0; ct < 8; ++ct) {
                bf16x8 b = *(const bf16x8*)(sBu + cur * WSLICE + ct * 512 + lane * 8);
                acc2[ct] = __builtin_amdgcn_mfma_f32_16x16x32_bf16(a[ks], b, acc2[ct], 0, 0, 0);
            }
        }
        __syncthreads();
        cur ^= 1;
    }

    #pragma unroll
    for (int ct = 0; ct < 8; ++ct) {
        int col = ct * 16 + lane16;
        float b1v = b1[col];
        #pragma unroll
        for (int r = 0; r < 4; ++r) {
            int node = nbase + we0 + lg * 4 + r;
            if (node < NN) {
                C1[(size_t)node * D + col] = f2b(acc1[ct][r] + b1v);
                R1[(size_t)node * D + col] = f2b(acc2[ct][r]);
            }
        }
    }
}

// ---------------- per-node segmented aggregation: atomic-free ----------------
// 16 lanes per node; node's edges are contiguous [starts, starts+deg) in sorted arrays.
#define ACC8(RV, DI) {                                                     \
    _Pragma("unroll")                                                      \
    for (int k2 = 0; k2 < 8; ++k2) {                                       \
        float xx = c1f[k2] + b2f((ushort)(RV)[k2]) + (DI) * wd[k2];        \
        acc[k2] += xx / (1.0f + __expf(-xx));                              \
    } }

#define DO8(IDXR, DDR, KO, JO) {                                           \
    int r0_ = __shfl((IDXR), gl + (KO) + 0);                               \
    int r1_ = __shfl((IDXR), gl + (KO) + 1);                               \
    int r2_ = __shfl((IDXR), gl + (KO) + 2);                               \
    int r3_ = __shfl((IDXR), gl + (KO) + 3);                               \
    int r4_ = __shfl((IDXR), gl + (KO) + 4);                               \
    int r5_ = __shfl((IDXR), gl + (KO) + 5);                               \
    int r6_ = __shfl((IDXR), gl + (KO) + 6);                               \
    int r7_ = __shfl((IDXR), gl + (KO) + 7);                               \
    float d0_ = __shfl((DDR), gl + (KO) + 0);                              \
    float d1_ = __shfl((DDR), gl + (KO) + 1);                              \
    float d2_ = __shfl((DDR), gl + (KO) + 2);                              \
    float d3_ = __shfl((DDR), gl + (KO) + 3);                              \
    float d4_ = __shfl((DDR), gl + (KO) + 4);                              \
    float d5_ = __shfl((DDR), gl + (KO) + 5);                              \
    float d6_ = __shfl((DDR), gl + (KO) + 6);                              \
    float d7_ = __shfl((DDR), gl + (KO) + 7);                              \
    bf16x8 v0_ = *(const bf16x8*)(R1 + (size_t)r0_ * D + l * 8);           \
    bf16x8 v1_ = *(const bf16x8*)(R1 + (size_t)r1_ * D + l * 8);           \
    bf16x8 v2_ = *(const bf16x8*)(R1 + (size_t)r2_ * D + l * 8);           \
    bf16x8 v3_ = *(const bf16x8*)(R1 + (size_t)r3_ * D + l * 8);           \
    bf16x8 v4_ = *(const bf16x8*)(R1 + (size_t)r4_ * D + l * 8);           \
    bf16x8 v5_ = *(const bf16x8*)(R1 + (size_t)r5_ * D + l * 8);           \
    bf16x8 v6_ = *(const bf16x8*)(R1 + (size_t)r6_ * D + l * 8);           \
    bf16x8 v7_ = *(const bf16x8*)(R1 + (size_t)r7_ * D + l * 8);           \
    if ((JO) + 0 < dg) ACC8(v0_, d0_);                                     \
    if ((JO) + 1 < dg) ACC8(v1_, d1_);                                     \
    if ((JO) + 2 < dg) ACC8(v2_, d2_);                                     \
    if ((JO) + 3 < dg) ACC8(v3_, d3_);                                     \
    if ((JO) + 4 < dg) ACC8(v4_, d4_);                                     \
    if ((JO) + 5 < dg) ACC8(v5_, d5_);                                     \
    if ((JO) + 6 < dg) ACC8(v6_, d6_);                                     \
    if ((JO) + 7 < dg) ACC8(v7_, d7_);                                     \
    }

__global__ __launch_bounds__(256)
void k_edge2(const ushort* __restrict__ C1, const ushort* __restrict__ R1,
             const int* __restrict__ srow, const float* __restrict__ sdist,
             const unsigned int* __restrict__ starts, const unsigned int* __restrict__ degi,
             const float* __restrict__ w1f, float* __restrict__ Hagg) {
    const int t = threadIdx.x;
    const int node = blockIdx.x * 16 + (t >> 4);
    const int l = t & 15;
    const int gl = t & 48;            // 16-lane group base within the wave

    const int base = (int)starts[node];
    const int dg   = (int)degi[node];

    float acc[8] = {0.f, 0.f, 0.f, 0.f, 0.f, 0.f, 0.f, 0.f};

    if (dg > 0) {
        float wd[8], c1f[8];
        #pragma unroll
        for (int i = 0; i < 8; ++i) wd[i] = w1f[256 * D + l * 8 + i];
        bf16x8 c1 = *(const bf16x8*)(C1 + (size_t)node * D + l * 8);
        #pragma unroll
        for (int i = 0; i < 8; ++i) c1f[i] = b2f((ushort)c1[i]);

        // cooperative preload of indices/dists: lane l holds edges l, 16+l, 32+l, 48+l (clamped)
        int  idx0, idx1 = 0, idx2 = 0, idx3 = 0;
        float dd0, dd1 = 0.f, dd2 = 0.f, dd3 = 0.f;
        {
            int e0 = base + (l < dg ? l : dg - 1);
            idx0 = srow[e0]; dd0 = sdist[e0];
            if (dg > 16) {
                int e1 = base + (16 + l < dg ? 16 + l : dg - 1);
                idx1 = srow[e1]; dd1 = sdist[e1];
            }
            if (dg > 32) {
                int e2 = base + (32 + l < dg ? 32 + l : dg - 1);
                idx2 = srow[e2]; dd2 = sdist[e2];
            }
            if (dg > 48) {
                int e3 = base + (48 + l < dg ? 48 + l : dg - 1);
                idx3 = srow[e3]; dd3 = sdist[e3];
            }
        }

        DO8(idx0, dd0, 0, 0);
        DO8(idx0, dd0, 8, 8);
        if (dg > 16) { DO8(idx1, dd1, 0, 16); DO8(idx1, dd1, 8, 24); }
        if (dg > 32) { DO8(idx2, dd2, 0, 32); DO8(idx2, dd2, 8, 40); }
        if (dg > 48) {
            DO8(idx3, dd3, 0, 48);
            DO8(idx3, dd3, 8, 56);
            for (int j = 64; j < dg; ++j) {       // rare overflow tail
                int e = base + j;
                int row = srow[e]; float di = sdist[e];
                bf16x8 rv = *(const bf16x8*)(R1 + (size_t)row * D + l * 8);
                ACC8(rv, di);
            }
        }
    }

    f32x4 o0 = {acc[0], acc[1], acc[2], acc[3]};
    f32x4 o1 = {acc[4], acc[5], acc[6], acc[7]};
    *(f32x4*)(Hagg + (size_t)node * D + l * 8)     = o0;
    *(f32x4*)(Hagg + (size_t)node * D + l * 8 + 4) = o1;
}

// ---------------- fused node update: nodeMLP + Hagg@W2/deg + b2 + residual + LN ----------------
__global__ __launch_bounds__(256, 4)
void k_node(const float* __restrict__ h, const ushort* __restrict__ hbin,
            const float* __restrict__ Hagg, const unsigned int* __restrict__ degi,
            const ushort* __restrict__ pw1, const ushort* __restrict__ pwE2v,
            const ushort* __restrict__ pw2,
            const float* __restrict__ b1, const float* __restrict__ b2n,
            const float* __restrict__ b2e,
            const float* __restrict__ lng, const float* __restrict__ lnb,
            float* __restrict__ hout, ushort* __restrict__ hbout) {
    __shared__ ushort sBu[2 * WSLICE];    // 16 KB
    __shared__ ushort sHidu[64 * 128];    // 16 KB

    const int t = threadIdx.x;
    const int nbase = blockIdx.x * 64;
    const int lane = t & 63;
    const int wv = t >> 6;
    const int we0 = wv * 16;
    const int lane16 = lane & 15;
    const int lg = lane >> 4;
    const int ar = we0 + lane16;
    const int nodeA = nbase + ar;
    const int nclA = nodeA < NN ? nodeA : NN - 1;

    bf16x8 a_h[4], a_g[4];
    #pragma unroll
    for (int ks = 0; ks < 4; ++ks)
        a_h[ks] = *(const bf16x8*)(hbin + (size_t)nclA * D + (ks * 4 + lg) * 8);
    #pragma unroll
    for (int ks = 0; ks < 4; ++ks) {
        f32x4 u0 = *(const f32x4*)(Hagg + (size_t)nclA * D + (ks * 4 + lg) * 8);
        f32x4 u1 = *(const f32x4*)(Hagg + (size_t)nclA * D + (ks * 4 + lg) * 8 + 4);
        bf16x8 v;
        #pragma unroll
        for (int j = 0; j < 4; ++j) { v[j] = (short)f2b(u0[j]); v[4 + j] = (short)f2b(u1[j]); }
        a_g[ks] = v;
    }

    stage8k(pw1, sBu, t);
    __syncthreads();

    f32x4 acc1[8], acc2[8], acc3[8];
    #pragma unroll
    for (int ct = 0; ct < 8; ++ct) {
        acc1[ct] = (f32x4){0.f, 0.f, 0.f, 0.f};
        acc2[ct] = (f32x4){0.f, 0.f, 0.f, 0.f};
        acc3[ct] = (f32x4){0.f, 0.f, 0.f, 0.f};
    }

    int cur = 0;
    #pragma unroll
    for (int s = 0; s < 12; ++s) {
        if (s < 11) {
            const ushort* nsrc = (s + 1 < 4) ? (pw1 + (s + 1) * WSLICE)
                               : (s + 1 < 8) ? (pwE2v + (s + 1 - 4) * WSLICE)
                                             : (pw2 + (s + 1 - 8) * WSLICE);
            stage8k(nsrc, sBu + (cur ^ 1) * WSLICE, t);
        }
        if (s == 4) {
            // epilogue 1: silu(acc1 + b1) -> sHidu (wave-local rows, swizzled)
            #pragma unroll
            for (int ct = 0; ct < 8; ++ct) {
                int col = ct * 16 + lane16;
                float b1v = b1[col];
                #pragma unroll
                for (int r = 0; r < 4; ++r) {
                    int er = we0 + lg * 4 + r;
                    float v = silu_f(acc1[ct][r] + b1v);
                    int c2 = col >> 3;
                    sHidu[er * 128 + ((c2 ^ (er & 7)) * 8) + (col & 7)] = f2b(v);
                }
            }
        }
        if (s < 4) {
            #pragma unroll
            for (int ct = 0; ct < 8; ++ct) {
                bf16x8 b = *(const bf16x8*)(sBu + cur * WSLICE + ct * 512 + lane * 8);
                acc1[ct] = __builtin_amdgcn_mfma_f32_16x16x32_bf16(a_h[s], b, acc1[ct], 0, 0, 0);
            }
        } else if (s < 8) {
            #pragma unroll
            for (int ct = 0; ct < 8; ++ct) {
                bf16x8 b = *(const bf16x8*)(sBu + cur * WSLICE + ct * 512 + lane * 8);
                acc3[ct] = __builtin_amdgcn_mfma_f32_16x16x32_bf16(a_g[s - 4], b, acc3[ct], 0, 0, 0);
            }
        } else {
            int c = (s - 8) * 4 + lg;
            bf16x8 ah = *(const bf16x8*)(sHidu + ar * 128 + ((c ^ (ar & 7)) * 8));
            #pragma unroll
            for (int ct = 0; ct < 8; ++ct) {
                bf16x8 b = *(const bf16x8*)(sBu + cur * WSLICE + ct * 512 + lane * 8);
                acc2[ct] = __builtin_amdgcn_mfma_f32_16x16x32_bf16(ah, b, acc2[ct], 0, 0, 0);
            }
        }
        __syncthreads();
        cur ^= 1;
    }

    // y = h + nodeMLP(h) + b2n + Hagg@W2 * invd + [deg>0] b2e
    #pragma unroll
    for (int ct = 0; ct < 8; ++ct) {
        int col = ct * 16 + lane16;
        float b2nv = b2n[col];
        float b2ev = b2e[col];
        #pragma unroll
        for (int r = 0; r < 4; ++r) {
            int er = we0 + lg * 4 + r;
            int node = nbase + er;
            int ncl = node < NN ? node : NN - 1;
            unsigned int dg = degi[ncl];
            float invd = 1.0f / fmaxf((float)dg, 1.0f);
            float y = h[(size_t)ncl * D + col] + acc2[ct][r] + b2nv
                    + acc3[ct][r] * invd + (dg > 0 ? b2ev : 0.0f);
            acc2[ct][r] = y;
        }
    }

    #pragma unroll
    for (int r = 0; r < 4; ++r) {
        float s = 0.f, s2 = 0.f;
        #pragma unroll
        for (int ct = 0; ct < 8; ++ct) { float y = acc2[ct][r]; s += y; s2 += y * y; }
        #pragma unroll
        for (int off = 1; off < 16; off <<= 1) {
            s  += __shfl_xor(s,  off, 16);
            s2 += __shfl_xor(s2, off, 16);
        }
        float mean = s * (1.0f / D);
        float var  = s2 * (1.0f / D) - mean * mean;
        float rstd = rsqrtf(var + 1e-5f);
        int node = nbase + we0 + lg * 4 + r;
        if (node < NN) {
            #pragma unroll
            for (int ct = 0; ct < 8; ++ct) {
                int col = ct * 16 + lane16;
                float v = (acc2[ct][r] - mean) * rstd * lng[col] + lnb[col];
                hout[(size_t)node * D + col] = v;
                hbout[(size_t)node * D + col] = f2b(v);
            }
        }
    }
}

extern "C" void kernel_launch(void* const* d_in, const int* in_sizes, int n_in,
                              void* d_out, int out_size, void* d_ws, size_t ws_size,
                              hipStream_t stream) {
    const float* x        = (const float*)d_in[0];
    const float* pos      = (const float*)d_in[1];
    const float* time_emb = (const float*)d_in[2];
    const float* time_w1  = (const float*)d_in[3];
    const float* time_b1  = (const float*)d_in[4];
    const float* time_w2  = (const float*)d_in[5];
    const float* time_b2  = (const float*)d_in[6];
    const float* node_w1  = (const float*)d_in[7];
    const float* node_b1  = (const float*)d_in[8];
    const float* node_w2  = (const float*)d_in[9];
    const float* node_b2  = (const float*)d_in[10];
    const float* edge_w1  = (const float*)d_in[11];
    const float* edge_b1  = (const float*)d_in[12];
    const float* edge_w2  = (const float*)d_in[13];
    const float* edge_b2  = (const float*)d_in[14];
    const float* ln_g     = (const float*)d_in[15];
    const float* ln_b     = (const float*)d_in[16];
    const int*   ei       = (const int*)d_in[17];
    const int*   batch    = (const int*)d_in[18];

    float* h = (float*)d_out;                       // [NN, D]
    float* pos_out = h + (size_t)NN * D;            // [NN, 3]

    char* w = (char*)d_ws;
    float*        tp     = (float*)w;        w += (((size_t)NBATCH * D * 4) + 255) & ~(size_t)255;
    unsigned int* degi   = (unsigned int*)w; w += (((size_t)NN * 4) + 255) & ~(size_t)255;
    unsigned int* part   = (unsigned int*)w; w += 256;
    unsigned int* starts = (unsigned int*)w; w += (((size_t)NN * 4) + 255) & ~(size_t)255;
    unsigned int* cursor = (unsigned int*)w; w += (((size_t)NN * 4) + 255) & ~(size_t)255;
    int*          srow   = (int*)w;          w += (((size_t)NE * 4) + 255) & ~(size_t)255;
    int*          scol   = (int*)w;          w += (((size_t)NE * 4) + 255) & ~(size_t)255;
    float*        sdist  = (float*)w;        w += (((size_t)NE * 4) + 255) & ~(size_t)255;
    float*        Hagg   = (float*)w;        w += (((size_t)NN * D * 4) + 255) & ~(size_t)255;
    ushort*       hb     = (ushort*)w;       w += (((size_t)NN * D * 2) + 255) & ~(size_t)255;
    ushort*       C1     = (ushort*)w;       w += (((size_t)NN * D * 2) + 255) & ~(size_t)255;
    ushort*       R1     = (ushort*)w;       w += (((size_t)NN * D * 2) + 255) & ~(size_t)255;
    ushort*       pwA    = (ushort*)w;       w += (((size_t)NLAYERS * 16384 * 2) + 255) & ~(size_t)255;
    ushort*       pwB    = (ushort*)w;       w += (((size_t)NLAYERS * 16384 * 2) + 255) & ~(size_t)255;
    ushort*       pwE2   = (ushort*)w;       w += (((size_t)NLAYERS * 16384 * 2) + 255) & ~(size_t)255;
    ushort*       pwN1   = (ushort*)w;       w += (((size_t)NLAYERS * 16384 * 2) + 255) & ~(size_t)255;
    ushort*       pwN2   = (ushort*)w;       w += (((size_t)NLAYERS * 16384 * 2) + 255) & ~(size_t)255;

    hipMemsetAsync(degi, 0, (size_t)NN * 4, stream);
    k_time_mlp<<<NBATCH, D, 0, stream>>>(time_emb, time_w1, time_b1, time_w2, time_b2, tp);
    k_init_h<<<(NN * D) / 256, 256, 0, stream>>>(x, tp, batch, h, hb);
    k_deg<<<NE / 256, 256, 0, stream>>>(ei + NE, degi);

    k_scan_a<<<SCANB, 256, 0, stream>>>(degi, part);
    k_scan_b<<<1, 64, 0, stream>>>(part);
    k_scan_c<<<SCANB, 256, 0, stream>>>(degi, part, starts, cursor);
    k_sort<<<NE / 256, 256, 0, stream>>>(ei, cursor, srow, scol);
    k_dist<<<NE / 256, 256, 0, stream>>>(srow, scol, pos, sdist);

    // weight pre-pack (slice-major fragment layout, all 128x128)
    k_pack<<<(NLAYERS * 16384) / 256, 256, 0, stream>>>(edge_w1, pwA, 257 * 128, 16384);
    k_pack<<<(NLAYERS * 16384) / 256, 256, 0, stream>>>(edge_w1 + 128 * 128, pwB, 257 * 128, 16384);
    k_pack<<<(NLAYERS * 16384) / 256, 256, 0, stream>>>(edge_w2, pwE2, 128 * 128, 16384);
    k_pack<<<(NLAYERS * 16384) / 256, 256, 0, stream>>>(node_w1, pwN1, 128 * 128, 16384);
    k_pack<<<(NLAYERS * 16384) / 256, 256, 0, stream>>>(node_w2, pwN2, 128 * 128, 16384);

    const int NBLK = (NN + 63) / 64;
    for (int l = 0; l < NLAYERS; ++l) {
        k_c1r1<<<NBLK, 256, 0, stream>>>(hb,
            pwA + (size_t)l * 16384, pwB + (size_t)l * 16384,
            edge_b1 + (size_t)l * D, C1, R1);
        k_edge2<<<NN / 16, 256, 0, stream>>>(C1, R1, srow, sdist, starts, degi,
            edge_w1 + (size_t)l * (2 * D + 1) * D, Hagg);
        k_node<<<NBLK, 256, 0, stream>>>(h, hb, Hagg, degi,
            pwN1 + (size_t)l * 16384, pwE2 + (size_t)l * 16384, pwN2 + (size_t)l * 16384,
            node_b1 + (size_t)l * D, node_b2 + (size_t)l * D, edge_b2 + (size_t)l * D,
            ln_g + (size_t)l * D, ln_b + (size_t)l * D, h, hb);
    }
    hipMemcpyAsync(pos_out, pos, (size_t)NN * 3 * 4, hipMemcpyDeviceToDevice, stream);
}